// Round 2
// baseline (4748.585 us; speedup 1.0000x reference)
//
#include <hip/hip_runtime.h>

// GATClassifier on MI355X — round 2: correctness-first, ws footprint ~144MB
// (flash alignment, no att/eft materialization, sliced layer-2 aggregation).

#define NSd 8192
#define NNd 16384
#define NEd 131072

typedef unsigned short u16;
typedef unsigned int   u32;

__device__ __forceinline__ float bf2f(u16 u){ return __uint_as_float(((u32)u) << 16); }
__device__ __forceinline__ u16 f2bf(float f){
  u32 u = __float_as_uint(f);
  u += 0x7fffu + ((u >> 16) & 1u);
  return (u16)(u >> 16);
}
__device__ __forceinline__ float eluf(float x){ return x > 0.f ? x : expm1f(x); }
__device__ __forceinline__ float leaky(float x){ return x > 0.f ? x : 0.2f * x; }
__device__ __forceinline__ float ldin(const void* p, size_t i, int fl){
  return fl ? bf2f(((const u16*)p)[i]) : ((const float*)p)[i];
}
__device__ __forceinline__ void lse_merge(float& m, float& z, float om, float oz){
  float M = fmaxf(m, om);
  z = z * __expf(m - M) + oz * __expf(om - M);
  m = M;
}

// ------------------------- workspace layout (bytes) -------------------------
static constexpr size_t OFF_WF   = 0;          // f32 weight copies: 382339 floats
static constexpr size_t OFF_CB   = 1529600;    // combos: 13824 floats
static constexpr size_t OFF_X1A  = 1584896;    // 8192*64 f32
static constexpr size_t OFF_X2A  = 3682048;
static constexpr size_t OFF_HN0  = 5779200;    // 16384*64 f32
static constexpr size_t OFF_U    = 9973504;    // 131072*64 f32
static constexpr size_t OFF_AL1  = 43527936;   // 131072*8 f32
static constexpr size_t OFF_AL2  = 47722240;
static constexpr size_t OFF_HNA  = 51916544;   // 16384*512 f32
static constexpr size_t OFF_S    = 85470976;   // 131072*8 f32
static constexpr size_t OFF_AN   = 89665280;   // 16384*16 f32
static constexpr size_t OFF_M    = 90713856;   // 16384*8 f32
static constexpr size_t OFF_Z    = 91238144;
static constexpr size_t OFF_DEG  = 91762432;   // 16384 int
static constexpr size_t OFF_RP   = 91827968;   // 16385 int (padded)
static constexpr size_t OFF_FILL = 91893760;
static constexpr size_t OFF_CIDX = 91959296;   // 131072 int
static constexpr size_t OFF_RBIG = 92483584;   // 33554432: flash partials | g1 | hnB
static constexpr size_t OFF_SLY  = 126038016;  // slice y: 8192*512 bf16
static constexpr size_t OFF_SLG  = 134426624;  // slice g2: 1024*8*512 f32
static constexpr size_t OFF_XCAT = 151203840;  // 16*1024 f32
static constexpr size_t OFF_FLAG = 151269376;
static constexpr size_t WS_NEED  = 151269632;  // ~144.3 MB

// weight-copy element offsets (floats, within OFF_WF)
static constexpr int WO_PROJ = 0,      WO_W1 = 16384;
static constexpr int WO_AL1 = 49152,   WO_AR1 = 49664,  WO_AE1 = 50176;
static constexpr int WO_W2  = 50688;
static constexpr int WO_AL2 = 312832,  WO_AR2 = 313344, WO_AE2 = 313856;
static constexpr int WO_B1G = 314368,  WO_B1B = 315392;
static constexpr int WO_F1W = 316416,  WO_F1B = 381952;
static constexpr int WO_B2G = 382016,  WO_B2B = 382080;
static constexpr int WO_F2W = 382144,  WO_F2B = 382336;
static constexpr int WO_END = 382339;

// combo element offsets (floats, within OFF_CB)
static constexpr int CB_WC1 = 0;      // [16][64]  (o<8: W1.al1, o>=8: W1.ar1)
static constexpr int CB_WE1 = 1024;   // [8][64]   W1.ae1
static constexpr int CB_WC2 = 1536;   // [16][512] W2.al2 / W2.ar2
static constexpr int CB_WE2 = 9728;   // [8][512]  W2.ae2
static constexpr int CB_END = 13824;

// ------------------------------- dtype detect -------------------------------
__global__ __launch_bounds__(256) void detect_k(const u16* __restrict__ p, int* __restrict__ flag){
  __shared__ int bad;
  if (threadIdx.x == 0) bad = 0;
  __syncthreads();
  int b = 0;
  for (int i = threadIdx.x; i < 1024; i += 256){
    float f = bf2f(p[i]);
    if (!(fabsf(f) <= 100.f)) b++;
  }
  atomicAdd(&bad, b);
  __syncthreads();
  if (threadIdx.x == 0) *flag = (bad == 0) ? 1 : 0;
}

struct P17 { const void* p[17]; };

__global__ __launch_bounds__(256) void convw_k(P17 ps, float* __restrict__ wf, const int* __restrict__ flagp){
  const int i = blockIdx.x * 256 + threadIdx.x;
  if (i >= WO_END) return;
  const int fl = *flagp;
  const int ends[17] = {16384,49152,49664,50176,50688,312832,313344,313856,314368,
                        315392,316416,381952,382016,382080,382144,382336,382339};
  int seg = 0;
  while (i >= ends[seg]) seg++;
  const int start = seg ? ends[seg-1] : 0;
  wf[i] = ldin(ps.p[seg], i - start, fl);
}

__global__ __launch_bounds__(256) void combos_k(const float* __restrict__ wf, float* __restrict__ cb){
  const int i = blockIdx.x * 256 + threadIdx.x;
  if (i >= CB_END) return;
  float acc = 0.f;
  if (i < 1024){                 // WC1[o][d]
    const int o = i >> 6, d = i & 63, h = o & 7;
    const float* a = wf + ((o >> 3) ? WO_AR1 : WO_AL1) + h * 64;
    for (int dp = 0; dp < 64; dp++) acc += wf[WO_W1 + d * 512 + h * 64 + dp] * a[dp];
    cb[CB_WC1 + i] = acc;
  } else if (i < 1536){          // WE1[h][d]
    const int j = i - 1024, h = j >> 6, d = j & 63;
    for (int dp = 0; dp < 64; dp++) acc += wf[WO_W1 + d * 512 + h * 64 + dp] * wf[WO_AE1 + h * 64 + dp];
    cb[CB_WE1 + j] = acc;
  } else if (i < 9728){          // WC2[o][c]
    const int j = i - 1536, o = j >> 9, c = j & 511, h = o & 7;
    const float* a = wf + ((o >> 3) ? WO_AR2 : WO_AL2) + h * 64;
    for (int dp = 0; dp < 64; dp++) acc += wf[WO_W2 + c * 512 + h * 64 + dp] * a[dp];
    cb[CB_WC2 + j] = acc;
  } else {                       // WE2[h][c]
    const int j = i - 9728, h = j >> 9, c = j & 511;
    for (int dp = 0; dp < 64; dp++) acc += wf[WO_W2 + c * 512 + h * 64 + dp] * wf[WO_AE2 + h * 64 + dp];
    cb[CB_WE2 + j] = acc;
  }
}

// ------------------------------ flash alignment -----------------------------
// grid (128 q-tiles, 4 key-splits). partial acc (unnormalized) + m,l.
__global__ __launch_bounds__(256) void flash_part_k(const void* __restrict__ Qp, const void* __restrict__ Kp,
                                                    const int* __restrict__ flagp, float* __restrict__ pacc,
                                                    float* __restrict__ pm, float* __restrict__ pz){
  const int fl = *flagp;
  __shared__ float Qs[64][65], Ks[64][65], Ps[64][65];
  const int t = threadIdx.x, tx = t & 15, ty = t >> 4;
  const int q0 = blockIdx.x * 64;
  const int kbeg = blockIdx.y * 2048;
  {
    const int r = t >> 2, c0 = (t & 3) * 16;
    if (fl){ for (int c = 0; c < 16; c++) Qs[r][c0+c] = bf2f(((const u16*)Qp)[(size_t)(q0+r)*64 + c0+c]); }
    else   { for (int c = 0; c < 16; c++) Qs[r][c0+c] = ((const float*)Qp)[(size_t)(q0+r)*64 + c0+c]; }
  }
  float acc[4][4] = {{0.f}};
  float m[4], l[4];
  #pragma unroll
  for (int i = 0; i < 4; i++){ m[i] = -1e30f; l[i] = 0.f; }

  for (int kt = 0; kt < 2048; kt += 64){
    __syncthreads();
    {
      const int r = t >> 2, c0 = (t & 3) * 16;
      if (fl){ for (int c = 0; c < 16; c++) Ks[r][c0+c] = bf2f(((const u16*)Kp)[(size_t)(kbeg+kt+r)*64 + c0+c]); }
      else   { for (int c = 0; c < 16; c++) Ks[r][c0+c] = ((const float*)Kp)[(size_t)(kbeg+kt+r)*64 + c0+c]; }
    }
    __syncthreads();
    float s[4][4] = {{0.f}};
    #pragma unroll
    for (int k = 0; k < 64; k++){
      float a0 = Qs[ty*4+0][k], a1 = Qs[ty*4+1][k], a2 = Qs[ty*4+2][k], a3 = Qs[ty*4+3][k];
      float b0 = Ks[tx*4+0][k], b1 = Ks[tx*4+1][k], b2 = Ks[tx*4+2][k], b3 = Ks[tx*4+3][k];
      s[0][0] = fmaf(a0,b0,s[0][0]); s[0][1] = fmaf(a0,b1,s[0][1]); s[0][2] = fmaf(a0,b2,s[0][2]); s[0][3] = fmaf(a0,b3,s[0][3]);
      s[1][0] = fmaf(a1,b0,s[1][0]); s[1][1] = fmaf(a1,b1,s[1][1]); s[1][2] = fmaf(a1,b2,s[1][2]); s[1][3] = fmaf(a1,b3,s[1][3]);
      s[2][0] = fmaf(a2,b0,s[2][0]); s[2][1] = fmaf(a2,b1,s[2][1]); s[2][2] = fmaf(a2,b2,s[2][2]); s[2][3] = fmaf(a2,b3,s[2][3]);
      s[3][0] = fmaf(a3,b0,s[3][0]); s[3][1] = fmaf(a3,b1,s[3][1]); s[3][2] = fmaf(a3,b2,s[3][2]); s[3][3] = fmaf(a3,b3,s[3][3]);
    }
    #pragma unroll
    for (int i = 0; i < 4; i++){
      float rm = fmaxf(fmaxf(s[i][0], s[i][1]), fmaxf(s[i][2], s[i][3]));
      #pragma unroll
      for (int off = 1; off < 16; off <<= 1) rm = fmaxf(rm, __shfl_xor(rm, off));
      const float mn = fmaxf(m[i], rm);
      const float sc = __expf(m[i] - mn);
      float rs = 0.f;
      #pragma unroll
      for (int j = 0; j < 4; j++){ float p = __expf(s[i][j] - mn); s[i][j] = p; rs += p; }
      #pragma unroll
      for (int off = 1; off < 16; off <<= 1) rs += __shfl_xor(rs, off);
      l[i] = l[i] * sc + rs; m[i] = mn;
      #pragma unroll
      for (int j = 0; j < 4; j++){ acc[i][j] *= sc; Ps[ty*4+i][tx*4+j] = s[i][j]; }
    }
    __syncthreads();
    #pragma unroll
    for (int k = 0; k < 64; k++){
      float p0 = Ps[ty*4+0][k], p1 = Ps[ty*4+1][k], p2 = Ps[ty*4+2][k], p3 = Ps[ty*4+3][k];
      float v0 = Ks[k][tx*4+0], v1 = Ks[k][tx*4+1], v2 = Ks[k][tx*4+2], v3 = Ks[k][tx*4+3];
      acc[0][0] = fmaf(p0,v0,acc[0][0]); acc[0][1] = fmaf(p0,v1,acc[0][1]); acc[0][2] = fmaf(p0,v2,acc[0][2]); acc[0][3] = fmaf(p0,v3,acc[0][3]);
      acc[1][0] = fmaf(p1,v0,acc[1][0]); acc[1][1] = fmaf(p1,v1,acc[1][1]); acc[1][2] = fmaf(p1,v2,acc[1][2]); acc[1][3] = fmaf(p1,v3,acc[1][3]);
      acc[2][0] = fmaf(p2,v0,acc[2][0]); acc[2][1] = fmaf(p2,v1,acc[2][1]); acc[2][2] = fmaf(p2,v2,acc[2][2]); acc[2][3] = fmaf(p2,v3,acc[2][3]);
      acc[3][0] = fmaf(p3,v0,acc[3][0]); acc[3][1] = fmaf(p3,v1,acc[3][1]); acc[3][2] = fmaf(p3,v2,acc[3][2]); acc[3][3] = fmaf(p3,v3,acc[3][3]);
    }
  }
  #pragma unroll
  for (int i = 0; i < 4; i++){
    const int row = q0 + ty*4 + i;
    #pragma unroll
    for (int j = 0; j < 4; j++)
      pacc[((size_t)blockIdx.y * NSd + row) * 64 + tx*4 + j] = acc[i][j];
    if (tx == 0){ pm[blockIdx.y * NSd + row] = m[i]; pz[blockIdx.y * NSd + row] = l[i]; }
  }
}

__global__ __launch_bounds__(256) void flash_merge_k(const float* __restrict__ pacc, const float* __restrict__ pm,
                                                     const float* __restrict__ pz, float* __restrict__ outp){
  const int t = threadIdx.x;
  const int r = blockIdx.x * 4 + (t >> 6);
  const int d = t & 63;
  float M = -1e30f;
  #pragma unroll
  for (int s = 0; s < 4; s++) M = fmaxf(M, pm[s * NSd + r]);
  float Zt = 0.f, v = 0.f;
  #pragma unroll
  for (int s = 0; s < 4; s++){
    const float w = __expf(pm[s * NSd + r] - M);
    Zt += pz[s * NSd + r] * w;
    v  += pacc[((size_t)s * NSd + r) * 64 + d] * w;
  }
  outp[(size_t)r * 64 + d] = v / Zt;
}

// ------------------------------- projection ---------------------------------
// hn0 = relu([nbd, xa, nbd-xa, nbd*xa] @ projW)  M=16384 N=64 K=256
__global__ __launch_bounds__(256) void proj_k(const void* __restrict__ nbd1, const void* __restrict__ nbd2,
                                              const float* __restrict__ x1a, const float* __restrict__ x2a,
                                              const float* __restrict__ wf, float* __restrict__ hn0,
                                              const int* __restrict__ flagp){
  const int fl = *flagp;
  __shared__ float At[64][65], Bt[64][65];
  const int t = threadIdx.x, tx = t & 15, ty = t >> 4;
  const int m0 = blockIdx.x * 64;
  float acc[4][4] = {{0.f}};
  for (int kt = 0; kt < 256; kt += 64){
    __syncthreads();
    {
      const int i = t >> 2, c0 = (t & 3) * 16;
      const int mrow = m0 + i;
      const int side = mrow < NSd;
      const int mr = side ? mrow : mrow - NSd;
      const void* nb = side ? nbd1 : nbd2;
      const float* xa = side ? x1a : x2a;
      const int seg = kt >> 6;
      for (int c = 0; c < 16; c++){
        const int kk = c0 + c;
        const float nv = ldin(nb, (size_t)mr * 64 + kk, fl);
        const float av = xa[(size_t)mr * 64 + kk];
        At[i][kk] = (seg == 0) ? nv : (seg == 1) ? av : (seg == 2) ? (nv - av) : (nv * av);
      }
      const int kk = t >> 2;
      for (int c = 0; c < 16; c++) Bt[kk][c0 + c] = wf[WO_PROJ + (kt + kk) * 64 + c0 + c];
    }
    __syncthreads();
    #pragma unroll
    for (int k = 0; k < 64; k++){
      float a0 = At[ty*4+0][k], a1 = At[ty*4+1][k], a2 = At[ty*4+2][k], a3 = At[ty*4+3][k];
      float b0 = Bt[k][tx*4+0], b1 = Bt[k][tx*4+1], b2 = Bt[k][tx*4+2], b3 = Bt[k][tx*4+3];
      acc[0][0] = fmaf(a0,b0,acc[0][0]); acc[0][1] = fmaf(a0,b1,acc[0][1]); acc[0][2] = fmaf(a0,b2,acc[0][2]); acc[0][3] = fmaf(a0,b3,acc[0][3]);
      acc[1][0] = fmaf(a1,b0,acc[1][0]); acc[1][1] = fmaf(a1,b1,acc[1][1]); acc[1][2] = fmaf(a1,b2,acc[1][2]); acc[1][3] = fmaf(a1,b3,acc[1][3]);
      acc[2][0] = fmaf(a2,b0,acc[2][0]); acc[2][1] = fmaf(a2,b1,acc[2][1]); acc[2][2] = fmaf(a2,b2,acc[2][2]); acc[2][3] = fmaf(a2,b3,acc[2][3]);
      acc[3][0] = fmaf(a3,b0,acc[3][0]); acc[3][1] = fmaf(a3,b1,acc[3][1]); acc[3][2] = fmaf(a3,b2,acc[3][2]); acc[3][3] = fmaf(a3,b3,acc[3][3]);
    }
  }
  #pragma unroll
  for (int i = 0; i < 4; i++)
    #pragma unroll
    for (int j = 0; j < 4; j++)
      hn0[(size_t)(m0 + ty*4 + i) * 64 + tx*4 + j] = fmaxf(acc[i][j], 0.f);
}

// ------------------------------ small kernels -------------------------------
template<int K>
__global__ __launch_bounds__(256) void an_k(const float* __restrict__ in, const float* __restrict__ wc,
                                            float* __restrict__ an){
  const int id = blockIdx.x * 256 + threadIdx.x;   // 16384*16
  const int n = id >> 4, o = id & 15;
  float acc = 0.f;
  const float* row = in + (size_t)n * K;
  const float* w = wc + o * K;
  for (int c = 0; c < K; c++) acc = fmaf(row[c], w[c], acc);
  an[id] = acc;
}

__global__ __launch_bounds__(256) void u_k(const void* __restrict__ ebd, const float* __restrict__ hn0,
                                           const int* __restrict__ src, float* __restrict__ U,
                                           const int* __restrict__ flagp){
  const int fl = *flagp;
  const int id = blockIdx.x * 256 + threadIdx.x;   // 131072*64
  const int e = id >> 6, d = id & 63;
  U[id] = ldin(ebd, id, fl) + hn0[(size_t)src[e] * 64 + d];
}

__global__ __launch_bounds__(256) void s1_k(const void* __restrict__ ebd, const float* __restrict__ cb,
                                            const int* __restrict__ src, const int* __restrict__ dst,
                                            const float* __restrict__ an, float* __restrict__ S,
                                            const int* __restrict__ flagp){
  const int fl = *flagp;
  const int id = blockIdx.x * 256 + threadIdx.x;   // 131072*8
  const int e = id >> 3, h = id & 7;
  float a3 = 0.f;
  const float* w = cb + CB_WE1 + h * 64;
  for (int d = 0; d < 64; d++) a3 = fmaf(ldin(ebd, (size_t)e * 64 + d, fl), w[d], a3);
  const float a = an[src[e] * 16 + h] + a3 + an[dst[e] * 16 + 8 + h];
  S[id] = leaky(a);
}

// per (n,h) wave: segment max+sumexp over CSR
__global__ __launch_bounds__(256) void segsm_k(const float* __restrict__ S, const int* __restrict__ rp,
                                               const int* __restrict__ cidx, float* __restrict__ M,
                                               float* __restrict__ Z){
  const int w = blockIdx.x * 4 + (threadIdx.x >> 6);
  const int lane = threadIdx.x & 63;
  const int n = w >> 3, h = w & 7;
  const int beg = rp[n], end = rp[n + 1];
  float m = -1e30f, z = 0.f;
  for (int base = beg; base < end; base += 64){
    const int idx = base + lane;
    float v = -1e30f, cc = 0.f;
    if (idx < end){ v = S[(size_t)cidx[idx] * 8 + h]; cc = 1.f; }
    lse_merge(m, z, v, cc);
  }
  #pragma unroll
  for (int off = 32; off; off >>= 1){
    float om = __shfl_xor(m, off), oz = __shfl_xor(z, off);
    lse_merge(m, z, om, oz);
  }
  if (lane == 0){ M[n * 8 + h] = m; Z[n * 8 + h] = z; }
}

__global__ __launch_bounds__(256) void alpha_k(const float* __restrict__ S, const int* __restrict__ dst,
                                               const float* __restrict__ M, const float* __restrict__ Z,
                                               float* __restrict__ AL){
  const int id = blockIdx.x * 256 + threadIdx.x;   // 131072*8
  const int e = id >> 3, h = id & 7;
  const int d = dst[e];
  AL[id] = __expf(S[id] - M[d * 8 + h]) / fmaxf(Z[d * 8 + h], 1e-9f);
}

// g1[n,h,d] = sum_e alpha1[e,h] * u[e,d]
__global__ __launch_bounds__(256) void g1_k(const float* __restrict__ AL, const float* __restrict__ U,
                                            const int* __restrict__ rp, const int* __restrict__ cidx,
                                            float* __restrict__ G1){
  const int w = blockIdx.x * 4 + (threadIdx.x >> 6);
  const int lane = threadIdx.x & 63;
  const int n = w >> 3, h = w & 7;
  const int beg = rp[n], end = rp[n + 1];
  float acc = 0.f;
  for (int idx = beg; idx < end; idx++){
    const int e = cidx[idx];
    acc = fmaf(AL[(size_t)e * 8 + h], U[(size_t)e * 64 + lane], acc);
  }
  G1[(size_t)(n * 8 + h) * 64 + lane] = acc;
}

// hnA[n,c] = elu( sum_d g1[n, c>>6, d] * W1[d, c] )
__global__ __launch_bounds__(256) void nft1_k(const float* __restrict__ G1, const float* __restrict__ wf,
                                              float* __restrict__ HNA){
  const int id = blockIdx.x * 256 + threadIdx.x;   // 16384*512
  const int n = id >> 9, c = id & 511, h = c >> 6;
  const float* g = G1 + (size_t)(n * 8 + h) * 64;
  float acc = 0.f;
  for (int d = 0; d < 64; d++) acc = fmaf(g[d], wf[WO_W1 + d * 512 + c], acc);
  HNA[id] = eluf(acc);
}

// fused: s2[e,h'] = leaky(a1_2[src] + <eft2[e,h'],ae2[h']> + a2_2[dst])
// where eft2 row is recomputed from u via W1 (h-blocked) without materializing.
__global__ __launch_bounds__(256) void s2_k(const float* __restrict__ U, const float* __restrict__ AL1,
                                            const float* __restrict__ wf, const float* __restrict__ cb,
                                            const int* __restrict__ src, const int* __restrict__ dst,
                                            const float* __restrict__ an2, float* __restrict__ S){
  __shared__ float Us[64][65], Ws[64][65], Ps[64][65];
  const int t = threadIdx.x, tx = t & 15, ty = t >> 4;
  const int e0 = blockIdx.x * 64;
  {
    const int i = t >> 2, c0 = (t & 3) * 16;
    for (int c = 0; c < 16; c++) Us[i][c0 + c] = U[(size_t)(e0 + i) * 64 + c0 + c];
  }
  float acc2[2] = {0.f, 0.f};
  const int ei = t & 63, h0 = (t >> 6) * 2;
  for (int h = 0; h < 8; h++){
    __syncthreads();
    {
      const int d = t >> 2, c0 = (t & 3) * 16;
      for (int c = 0; c < 16; c++) Ws[d][c0 + c] = wf[WO_W1 + d * 512 + h * 64 + c0 + c];
    }
    __syncthreads();
    float s[4][4] = {{0.f}};
    #pragma unroll
    for (int k = 0; k < 64; k++){
      float a0 = Us[ty*4+0][k], a1 = Us[ty*4+1][k], a2 = Us[ty*4+2][k], a3 = Us[ty*4+3][k];
      float b0 = Ws[k][tx*4+0], b1 = Ws[k][tx*4+1], b2 = Ws[k][tx*4+2], b3 = Ws[k][tx*4+3];
      s[0][0] = fmaf(a0,b0,s[0][0]); s[0][1] = fmaf(a0,b1,s[0][1]); s[0][2] = fmaf(a0,b2,s[0][2]); s[0][3] = fmaf(a0,b3,s[0][3]);
      s[1][0] = fmaf(a1,b0,s[1][0]); s[1][1] = fmaf(a1,b1,s[1][1]); s[1][2] = fmaf(a1,b2,s[1][2]); s[1][3] = fmaf(a1,b3,s[1][3]);
      s[2][0] = fmaf(a2,b0,s[2][0]); s[2][1] = fmaf(a2,b1,s[2][1]); s[2][2] = fmaf(a2,b2,s[2][2]); s[2][3] = fmaf(a2,b3,s[2][3]);
      s[3][0] = fmaf(a3,b0,s[3][0]); s[3][1] = fmaf(a3,b1,s[3][1]); s[3][2] = fmaf(a3,b2,s[3][2]); s[3][3] = fmaf(a3,b3,s[3][3]);
    }
    #pragma unroll
    for (int i = 0; i < 4; i++){
      const float al = AL1[(size_t)(e0 + ty*4 + i) * 8 + h];
      #pragma unroll
      for (int j = 0; j < 4; j++) Ps[ty*4+i][tx*4+j] = eluf(al * s[i][j]);
    }
    __syncthreads();
    for (int k = 0; k < 64; k++){
      const float p = Ps[ei][k];
      acc2[0] = fmaf(p, cb[CB_WE2 + (h0 + 0) * 512 + h * 64 + k], acc2[0]);
      acc2[1] = fmaf(p, cb[CB_WE2 + (h0 + 1) * 512 + h * 64 + k], acc2[1]);
    }
  }
  const int e = e0 + ei;
  const int se = src[e], de = dst[e];
  #pragma unroll
  for (int y = 0; y < 2; y++){
    const int hp = h0 + y;
    S[(size_t)e * 8 + hp] = leaky(an2[se * 16 + hp] + acc2[y] + an2[de * 16 + 8 + hp]);
  }
}

// slice y: y[ep,c] = elu(alpha1[e, c>>6] * (u[e]@W1[:,c])) + hnA[src[e], c]   (bf16)
__global__ __launch_bounds__(256) void y_k(const float* __restrict__ U, const float* __restrict__ AL1,
                                           const float* __restrict__ HNA, const float* __restrict__ wf,
                                           const int* __restrict__ src, const int* __restrict__ cidx,
                                           u16* __restrict__ Y, const int s){
  __shared__ float Us[64][65], Ws[64][65];
  __shared__ int Es[64], Ss[64];
  const int t = threadIdx.x, tx = t & 15, ty = t >> 4;
  const int ep0 = s * 8192 + blockIdx.x * 64;
  if (t < 64){ const int e = cidx[ep0 + t]; Es[t] = e; Ss[t] = src[e]; }
  __syncthreads();
  {
    const int i = t >> 2, c0 = (t & 3) * 16;
    const size_t rb = (size_t)Es[i] * 64;
    for (int c = 0; c < 16; c++) Us[i][c0 + c] = U[rb + c0 + c];
  }
  for (int h = 0; h < 8; h++){
    __syncthreads();
    {
      const int d = t >> 2, c0 = (t & 3) * 16;
      for (int c = 0; c < 16; c++) Ws[d][c0 + c] = wf[WO_W1 + d * 512 + h * 64 + c0 + c];
    }
    __syncthreads();
    float sv[4][4] = {{0.f}};
    #pragma unroll
    for (int k = 0; k < 64; k++){
      float a0 = Us[ty*4+0][k], a1 = Us[ty*4+1][k], a2 = Us[ty*4+2][k], a3 = Us[ty*4+3][k];
      float b0 = Ws[k][tx*4+0], b1 = Ws[k][tx*4+1], b2 = Ws[k][tx*4+2], b3 = Ws[k][tx*4+3];
      sv[0][0] = fmaf(a0,b0,sv[0][0]); sv[0][1] = fmaf(a0,b1,sv[0][1]); sv[0][2] = fmaf(a0,b2,sv[0][2]); sv[0][3] = fmaf(a0,b3,sv[0][3]);
      sv[1][0] = fmaf(a1,b0,sv[1][0]); sv[1][1] = fmaf(a1,b1,sv[1][1]); sv[1][2] = fmaf(a1,b2,sv[1][2]); sv[1][3] = fmaf(a1,b3,sv[1][3]);
      sv[2][0] = fmaf(a2,b0,sv[2][0]); sv[2][1] = fmaf(a2,b1,sv[2][1]); sv[2][2] = fmaf(a2,b2,sv[2][2]); sv[2][3] = fmaf(a2,b3,sv[2][3]);
      sv[3][0] = fmaf(a3,b0,sv[3][0]); sv[3][1] = fmaf(a3,b1,sv[3][1]); sv[3][2] = fmaf(a3,b2,sv[3][2]); sv[3][3] = fmaf(a3,b3,sv[3][3]);
    }
    #pragma unroll
    for (int i = 0; i < 4; i++){
      const int r = ty*4 + i;
      const float al = AL1[(size_t)Es[r] * 8 + h];
      const float* ha = HNA + (size_t)Ss[r] * 512 + h * 64 + tx*4;
      #pragma unroll
      for (int j = 0; j < 4; j++){
        const float v = eluf(al * sv[i][j]) + ha[j];
        Y[(size_t)(blockIdx.x * 64 + r) * 512 + h * 64 + tx*4 + j] = f2bf(v);
      }
    }
  }
}

// slice g2: g2[nl,h,c] = sum_{e->n} alpha2[e,h] * y[ep,c]
__global__ __launch_bounds__(256) void g2_k(const float* __restrict__ AL2, const u16* __restrict__ Y,
                                            const int* __restrict__ rp, const int* __restrict__ cidx,
                                            float* __restrict__ G2, const int s){
  const int t = threadIdx.x;
  const int nl = blockIdx.x;              // 0..1023
  const int n = s * 1024 + nl;
  const int d4 = (t & 127) * 4;
  const int hh = (t >> 7) * 4;
  const int beg = rp[n], end = rp[n + 1];
  const int base = s * 8192;
  float acc[4][4] = {{0.f}};
  for (int pos = beg; pos < end; pos++){
    const int e = cidx[pos];
    const int epl = pos - base;
    const float4 a4 = *(const float4*)(AL2 + (size_t)e * 8 + hh);
    const ushort4 yv = *(const ushort4*)(Y + (size_t)epl * 512 + d4);
    const float y0 = bf2f(yv.x), y1 = bf2f(yv.y), y2 = bf2f(yv.z), y3 = bf2f(yv.w);
    acc[0][0] = fmaf(a4.x, y0, acc[0][0]); acc[0][1] = fmaf(a4.x, y1, acc[0][1]); acc[0][2] = fmaf(a4.x, y2, acc[0][2]); acc[0][3] = fmaf(a4.x, y3, acc[0][3]);
    acc[1][0] = fmaf(a4.y, y0, acc[1][0]); acc[1][1] = fmaf(a4.y, y1, acc[1][1]); acc[1][2] = fmaf(a4.y, y2, acc[1][2]); acc[1][3] = fmaf(a4.y, y3, acc[1][3]);
    acc[2][0] = fmaf(a4.z, y0, acc[2][0]); acc[2][1] = fmaf(a4.z, y1, acc[2][1]); acc[2][2] = fmaf(a4.z, y2, acc[2][2]); acc[2][3] = fmaf(a4.z, y3, acc[2][3]);
    acc[3][0] = fmaf(a4.w, y0, acc[3][0]); acc[3][1] = fmaf(a4.w, y1, acc[3][1]); acc[3][2] = fmaf(a4.w, y2, acc[3][2]); acc[3][3] = fmaf(a4.w, y3, acc[3][3]);
  }
  #pragma unroll
  for (int hi = 0; hi < 4; hi++)
    #pragma unroll
    for (int di = 0; di < 4; di++)
      G2[((size_t)nl * 8 + hh + hi) * 512 + d4 + di] = acc[hi][di];
}

// slice nft2: hnB[n, h*64+d'] = elu( sum_c g2[nl,h,c] * W2[c, h*64+d'] )
__global__ __launch_bounds__(256) void nft2_k(const float* __restrict__ G2, const float* __restrict__ wf,
                                              float* __restrict__ HNB, const int s){
  __shared__ float At[64][65], Bt[64][65];
  const int t = threadIdx.x, tx = t & 15, ty = t >> 4;
  const int h = blockIdx.y;
  const int nl0 = blockIdx.x * 64;
  float acc[4][4] = {{0.f}};
  for (int kt = 0; kt < 512; kt += 64){
    __syncthreads();
    {
      const int i = t >> 2, c0 = (t & 3) * 16;
      for (int c = 0; c < 16; c++) At[i][c0 + c] = G2[((size_t)(nl0 + i) * 8 + h) * 512 + kt + c0 + c];
      const int kk = t >> 2;
      for (int c = 0; c < 16; c++) Bt[kk][c0 + c] = wf[WO_W2 + (size_t)(kt + kk) * 512 + h * 64 + c0 + c];
    }
    __syncthreads();
    #pragma unroll
    for (int k = 0; k < 64; k++){
      float a0 = At[ty*4+0][k], a1 = At[ty*4+1][k], a2 = At[ty*4+2][k], a3 = At[ty*4+3][k];
      float b0 = Bt[k][tx*4+0], b1 = Bt[k][tx*4+1], b2 = Bt[k][tx*4+2], b3 = Bt[k][tx*4+3];
      acc[0][0] = fmaf(a0,b0,acc[0][0]); acc[0][1] = fmaf(a0,b1,acc[0][1]); acc[0][2] = fmaf(a0,b2,acc[0][2]); acc[0][3] = fmaf(a0,b3,acc[0][3]);
      acc[1][0] = fmaf(a1,b0,acc[1][0]); acc[1][1] = fmaf(a1,b1,acc[1][1]); acc[1][2] = fmaf(a1,b2,acc[1][2]); acc[1][3] = fmaf(a1,b3,acc[1][3]);
      acc[2][0] = fmaf(a2,b0,acc[2][0]); acc[2][1] = fmaf(a2,b1,acc[2][1]); acc[2][2] = fmaf(a2,b2,acc[2][2]); acc[2][3] = fmaf(a2,b3,acc[2][3]);
      acc[3][0] = fmaf(a3,b0,acc[3][0]); acc[3][1] = fmaf(a3,b1,acc[3][1]); acc[3][2] = fmaf(a3,b2,acc[3][2]); acc[3][3] = fmaf(a3,b3,acc[3][3]);
    }
  }
  #pragma unroll
  for (int i = 0; i < 4; i++)
    #pragma unroll
    for (int j = 0; j < 4; j++)
      HNB[(size_t)(s * 1024 + nl0 + ty*4 + i) * 512 + h * 64 + tx*4 + j] = eluf(acc[i][j]);
}

// ---------------------------------- CSR -------------------------------------
__global__ __launch_bounds__(256) void hist_k(const int* __restrict__ dst, int* __restrict__ deg){
  const int e = blockIdx.x * 256 + threadIdx.x;
  if (e < NEd) atomicAdd(&deg[dst[e]], 1);
}
__global__ __launch_bounds__(256) void scan_k(const int* __restrict__ deg, int* __restrict__ rp,
                                              int* __restrict__ fill){
  __shared__ int ps[257];
  const int t = threadIdx.x;
  const int base = t * 64;
  int s = 0;
  for (int i = 0; i < 64; i++) s += deg[base + i];
  ps[t + 1] = s;
  if (t == 0) ps[0] = 0;
  __syncthreads();
  if (t == 0) for (int i = 1; i <= 256; i++) ps[i] += ps[i - 1];
  __syncthreads();
  int off = ps[t];
  for (int i = 0; i < 64; i++){ rp[base + i] = off; fill[base + i] = off; off += deg[base + i]; }
  if (t == 255) rp[NNd] = off;
}
__global__ __launch_bounds__(256) void scatter_k(const int* __restrict__ dst, int* __restrict__ fill,
                                                 int* __restrict__ cidx){
  const int e = blockIdx.x * 256 + threadIdx.x;
  if (e < NEd){ int pos = atomicAdd(&fill[dst[e]], 1); cidx[pos] = e; }
}

// ------------------------------- readout ------------------------------------
__global__ __launch_bounds__(256) void mean_k(const float* __restrict__ HNB, float* __restrict__ xcat){
  const int sg = blockIdx.x;   // 0..31
  const int t = threadIdx.x;
  const int g = (sg < 16) ? sg : sg - 16;
  const int half = (sg < 16) ? 0 : 1;
  for (int c = t; c < 512; c += 256){
    float s = 0.f;
    const float* base = HNB + (size_t)sg * 512 * 512 + c;
    for (int n = 0; n < 512; n++) s += base[(size_t)n * 512];
    xcat[g * 1024 + half * 512 + c] = s * (1.f / 512.f);
  }
}

__global__ __launch_bounds__(1024) void head_k(float* __restrict__ xcat, const float* __restrict__ wf,
                                               void* __restrict__ outp, const int* __restrict__ flagp){
  __shared__ float y1[16][64];
  __shared__ float y2[16][64];
  __shared__ float mu2s[64], sc2s[64];
  const int t = threadIdx.x;
  {
    float mu = 0.f;
    #pragma unroll
    for (int g = 0; g < 16; g++) mu += xcat[g * 1024 + t];
    mu *= (1.f / 16.f);
    float var = 0.f;
    #pragma unroll
    for (int g = 0; g < 16; g++){ float d = xcat[g * 1024 + t] - mu; var += d * d; }
    var *= (1.f / 16.f);
    const float sc = rsqrtf(var + 1e-5f) * wf[WO_B1G + t];
    const float sh = wf[WO_B1B + t] - mu * sc;
    #pragma unroll
    for (int g = 0; g < 16; g++) xcat[g * 1024 + t] = xcat[g * 1024 + t] * sc + sh;
  }
  __syncthreads();
  {
    const int gg = t >> 6, c = t & 63;
    float acc = wf[WO_F1B + c];
    for (int k = 0; k < 1024; k++) acc = fmaf(xcat[gg * 1024 + k], wf[WO_F1W + k * 64 + c], acc);
    y1[gg][c] = fmaxf(acc, 0.f);
  }
  __syncthreads();
  if (t < 64){
    float mu = 0.f;
    #pragma unroll
    for (int g = 0; g < 16; g++) mu += y1[g][t];
    mu *= (1.f / 16.f);
    float var = 0.f;
    #pragma unroll
    for (int g = 0; g < 16; g++){ float d = y1[g][t] - mu; var += d * d; }
    var *= (1.f / 16.f);
    mu2s[t] = mu; sc2s[t] = rsqrtf(var + 1e-5f) * wf[WO_B2G + t];
  }
  __syncthreads();
  {
    const int gg = t >> 6, c = t & 63;
    y2[gg][c] = (y1[gg][c] - mu2s[c]) * sc2s[c] + wf[WO_B2B + c];
  }
  __syncthreads();
  if (t < 48){
    const int gg = t / 3, c = t % 3;
    float acc = wf[WO_F2B + c];
    #pragma unroll
    for (int k = 0; k < 64; k++) acc = fmaf(y2[gg][k], wf[WO_F2W + k * 3 + c], acc);
    if (*flagp) ((u16*)outp)[t] = f2bf(acc);
    else        ((float*)outp)[t] = acc;
  }
}

// --------------------------------- launch -----------------------------------
extern "C" void kernel_launch(void* const* d_in, const int* in_sizes, int n_in,
                              void* d_out, int out_size, void* d_ws, size_t ws_size,
                              hipStream_t stream) {
  (void)in_sizes; (void)n_in; (void)out_size;
  if (ws_size < WS_NEED) return;

  const int* src = (const int*)d_in[3];
  const int* dst = (const int*)d_in[4];
  char* w = (char*)d_ws;

  float* wf   = (float*)(w + OFF_WF);
  float* cb   = (float*)(w + OFF_CB);
  float* x1a  = (float*)(w + OFF_X1A);
  float* x2a  = (float*)(w + OFF_X2A);
  float* hn0  = (float*)(w + OFF_HN0);
  float* U    = (float*)(w + OFF_U);
  float* AL1  = (float*)(w + OFF_AL1);
  float* AL2  = (float*)(w + OFF_AL2);
  float* HNA  = (float*)(w + OFF_HNA);
  float* S    = (float*)(w + OFF_S);
  float* AN   = (float*)(w + OFF_AN);
  float* M    = (float*)(w + OFF_M);
  float* Z    = (float*)(w + OFF_Z);
  int*   deg  = (int*)(w + OFF_DEG);
  int*   rp   = (int*)(w + OFF_RP);
  int*   fill = (int*)(w + OFF_FILL);
  int*   cidx = (int*)(w + OFF_CIDX);
  float* rbig = (float*)(w + OFF_RBIG);
  u16*   Y    = (u16*)(w + OFF_SLY);
  float* G2   = (float*)(w + OFF_SLG);
  float* xcat = (float*)(w + OFF_XCAT);
  int*   flag = (int*)(w + OFF_FLAG);

  // flash partial views inside rbig
  float* pacc = rbig;
  float* pm   = (float*)(w + OFF_RBIG + 8388608);
  float* pz   = (float*)(w + OFF_RBIG + 8388608 + 131072);
  float* G1   = rbig;           // after flash dead
  float* HNB  = rbig;           // after g1 dead

  // 0. dtype detect + weight conversion + combos
  detect_k<<<1, 256, 0, stream>>>((const u16*)d_in[0], flag);
  P17 ps;
  for (int i = 0; i < 17; i++) ps.p[i] = d_in[6 + i];
  convw_k<<<(WO_END + 255) / 256, 256, 0, stream>>>(ps, wf, flag);
  combos_k<<<(CB_END + 255) / 256, 256, 0, stream>>>(wf, cb);

  // 1. CSR over dst
  hipMemsetAsync(deg, 0, NNd * sizeof(int), stream);
  hist_k<<<NEd / 256, 256, 0, stream>>>(dst, deg);
  scan_k<<<1, 256, 0, stream>>>(deg, rp, fill);
  scatter_k<<<NEd / 256, 256, 0, stream>>>(dst, fill, cidx);

  // 2. alignment (flash, no att materialization)
  flash_part_k<<<dim3(128, 4), 256, 0, stream>>>(d_in[0], d_in[1], flag, pacc, pm, pz);
  flash_merge_k<<<NSd / 4, 256, 0, stream>>>(pacc, pm, pz, x1a);
  flash_part_k<<<dim3(128, 4), 256, 0, stream>>>(d_in[1], d_in[0], flag, pacc, pm, pz);
  flash_merge_k<<<NSd / 4, 256, 0, stream>>>(pacc, pm, pz, x2a);

  // 3. projection
  proj_k<<<NNd / 64, 256, 0, stream>>>(d_in[0], d_in[1], x1a, x2a, wf, hn0, flag);

  // 4. GAT layer 1 (never materializes ft/eft)
  an_k<64><<<NNd * 16 / 256, 256, 0, stream>>>(hn0, cb + CB_WC1, AN);
  u_k<<<NEd * 64 / 256, 256, 0, stream>>>(d_in[2], hn0, src, U, flag);
  s1_k<<<NEd * 8 / 256, 256, 0, stream>>>(d_in[2], cb, src, dst, AN, S, flag);
  segsm_k<<<NNd * 8 / 4, 256, 0, stream>>>(S, rp, cidx, M, Z);
  alpha_k<<<NEd * 8 / 256, 256, 0, stream>>>(S, dst, M, Z, AL1);
  g1_k<<<NNd * 8 / 4, 256, 0, stream>>>(AL1, U, rp, cidx, G1);
  nft1_k<<<NNd * 512 / 256, 256, 0, stream>>>(G1, wf, HNA);

  // 5. GAT layer 2 scores
  an_k<512><<<NNd * 16 / 256, 256, 0, stream>>>(HNA, cb + CB_WC2, AN);
  s2_k<<<NEd / 64, 256, 0, stream>>>(U, AL1, wf, cb, src, dst, AN, S);
  segsm_k<<<NNd * 8 / 4, 256, 0, stream>>>(S, rp, cidx, M, Z);
  alpha_k<<<NEd * 8 / 256, 256, 0, stream>>>(S, dst, M, Z, AL2);

  // 6. layer 2 aggregation in 16 static 2-graph slices (8192 edges each)
  for (int s = 0; s < 16; s++){
    y_k<<<128, 256, 0, stream>>>(U, AL1, HNA, wf, src, cidx, Y, s);
    g2_k<<<1024, 256, 0, stream>>>(AL2, Y, rp, cidx, G2, s);
    nft2_k<<<dim3(16, 8), 256, 0, stream>>>(G2, wf, HNB, s);
  }

  // 7. readout
  mean_k<<<32, 256, 0, stream>>>(HNB, xcat);
  head_k<<<1, 1024, 0, stream>>>(xcat, wf, d_out, flag);
}

// Round 3
// 3156.284 us; speedup vs baseline: 1.5045x; 1.5045x over previous
//
#include <hip/hip_runtime.h>

// GATClassifier on MI355X — round 3: s2 eliminated (fused a3 kernel),
// MFMA bf16 flash alignment, NS=8 slice loop with bf16 G2, folded alpha,
// block-per-node helpers. ws footprint 144.98 MB (known-safe).

#define NSd 8192
#define NNd 16384
#define NEd 131072

typedef unsigned short u16;
typedef unsigned int   u32;
typedef short bf16x8 __attribute__((ext_vector_type(8)));
typedef float f32x4  __attribute__((ext_vector_type(4)));

__device__ __forceinline__ float bf2f(u16 u){ return __uint_as_float(((u32)u) << 16); }
__device__ __forceinline__ u16 f2bf(float f){
  u32 u = __float_as_uint(f);
  u += 0x7fffu + ((u >> 16) & 1u);
  return (u16)(u >> 16);
}
__device__ __forceinline__ float eluf(float x){ return x > 0.f ? x : expm1f(x); }
__device__ __forceinline__ float leaky(float x){ return x > 0.f ? x : 0.2f * x; }
__device__ __forceinline__ float ldin(const void* p, size_t i, int fl){
  return fl ? bf2f(((const u16*)p)[i]) : ((const float*)p)[i];
}
__device__ __forceinline__ void lse_merge(float& m, float& z, float om, float oz){
  float M = fmaxf(m, om);
  z = z * __expf(m - M) + oz * __expf(om - M);
  m = M;
}

// ------------------------- workspace layout (bytes) -------------------------
static constexpr size_t OFF_WF   = 0;            // 382339 f32 weights
static constexpr size_t OFF_CB   = 1529600;      // 13824 f32 combos
static constexpr size_t OFF_U    = 1584896;      // 131072*64 f32
static constexpr size_t OFF_AL1  = 35139328;     // 131072*8 f32
static constexpr size_t OFF_AL2  = 39333632;
static constexpr size_t OFF_HNA  = 43527936;     // 16384*512 f32
static constexpr size_t OFF_DEG  = 77082368;     // 16384 int
static constexpr size_t OFF_RP   = 77147904;     // 16385 int (padded)
static constexpr size_t OFF_FILL = 77213696;
static constexpr size_t OFF_CIDX = 77279232;     // 131072 int
static constexpr size_t OFF_RBIG = 77803520;     // 33.5MB: flash partials | G1 | HNB
static constexpr size_t OFF_T    = 111357952;    // 33.5MB union region
static constexpr size_t OFF_XCAT = 144912384;
static constexpr size_t OFF_FLAG = 144977920;
static constexpr size_t WS_NEED  = 144978176;    // 144.98 MB

// T-union sub-offsets (early phase)
static constexpr size_t T_X1A = 0;               // 8192*64 f32
static constexpr size_t T_X2A = 2097152;
static constexpr size_t T_HN0 = 4194304;         // 16384*64 f32
static constexpr size_t T_AN  = 8388608;         // 16384*16 f32
static constexpr size_t T_S   = 9437184;         // 131072*8 f32
// T-union sub-offsets (slice phase, NS=8)
static constexpr size_t T_Y   = 0;               // 16384*512 bf16
static constexpr size_t T_G2  = 16777216;        // 2048*8*512 bf16

// weight offsets (floats within OFF_WF)
static constexpr int WO_PROJ = 0,      WO_W1 = 16384;
static constexpr int WO_AL1 = 49152,   WO_AR1 = 49664,  WO_AE1 = 50176;
static constexpr int WO_W2  = 50688;
static constexpr int WO_AL2 = 312832,  WO_AR2 = 313344, WO_AE2 = 313856;
static constexpr int WO_B1G = 314368,  WO_B1B = 315392;
static constexpr int WO_F1W = 316416,  WO_F1B = 381952;
static constexpr int WO_B2G = 382016,  WO_B2B = 382080;
static constexpr int WO_F2W = 382144,  WO_F2B = 382336;
static constexpr int WO_END = 382339;

// combo offsets (floats within OFF_CB)
static constexpr int CB_WC1 = 0;      // [16][64]
static constexpr int CB_WE1 = 1024;   // [8][64]
static constexpr int CB_WC2 = 1536;   // [16][512]
static constexpr int CB_WE2 = 9728;   // [8][512]
static constexpr int CB_END = 13824;

// ------------------------------- dtype detect -------------------------------
__global__ __launch_bounds__(256) void detect_k(const u16* __restrict__ p, int* __restrict__ flag){
  __shared__ int bad;
  if (threadIdx.x == 0) bad = 0;
  __syncthreads();
  int b = 0;
  for (int i = threadIdx.x; i < 1024; i += 256){
    float f = bf2f(p[i]);
    if (!(fabsf(f) <= 100.f)) b++;
  }
  atomicAdd(&bad, b);
  __syncthreads();
  if (threadIdx.x == 0) *flag = (bad == 0) ? 1 : 0;
}

struct P17 { const void* p[17]; };

__global__ __launch_bounds__(256) void convw_k(P17 ps, float* __restrict__ wf, const int* __restrict__ flagp){
  const int i = blockIdx.x * 256 + threadIdx.x;
  if (i >= WO_END) return;
  const int fl = *flagp;
  const int ends[17] = {16384,49152,49664,50176,50688,312832,313344,313856,314368,
                        315392,316416,381952,382016,382080,382144,382336,382339};
  int seg = 0;
  while (i >= ends[seg]) seg++;
  const int start = seg ? ends[seg-1] : 0;
  wf[i] = ldin(ps.p[seg], i - start, fl);
}

__global__ __launch_bounds__(256) void combos_k(const float* __restrict__ wf, float* __restrict__ cb){
  const int i = blockIdx.x * 256 + threadIdx.x;
  if (i >= CB_END) return;
  float acc = 0.f;
  if (i < 1024){
    const int o = i >> 6, d = i & 63, h = o & 7;
    const float* a = wf + ((o >> 3) ? WO_AR1 : WO_AL1) + h * 64;
    for (int dp = 0; dp < 64; dp++) acc += wf[WO_W1 + d * 512 + h * 64 + dp] * a[dp];
    cb[CB_WC1 + i] = acc;
  } else if (i < 1536){
    const int j = i - 1024, h = j >> 6, d = j & 63;
    for (int dp = 0; dp < 64; dp++) acc += wf[WO_W1 + d * 512 + h * 64 + dp] * wf[WO_AE1 + h * 64 + dp];
    cb[CB_WE1 + j] = acc;
  } else if (i < 9728){
    const int j = i - 1536, o = j >> 9, c = j & 511, h = o & 7;
    const float* a = wf + ((o >> 3) ? WO_AR2 : WO_AL2) + h * 64;
    for (int dp = 0; dp < 64; dp++) acc += wf[WO_W2 + c * 512 + h * 64 + dp] * a[dp];
    cb[CB_WC2 + j] = acc;
  } else {
    const int j = i - 9728, h = j >> 9, c = j & 511;
    for (int dp = 0; dp < 64; dp++) acc += wf[WO_W2 + c * 512 + h * 64 + dp] * wf[WO_AE2 + h * 64 + dp];
    cb[CB_WE2 + j] = acc;
  }
}

// --------------------------- flash alignment (MFMA) -------------------------
// 64-row Q tile per block, 4 key-splits of 2048; 16x16x32 bf16 MFMA.
// C/D layout: col=lane&15, row=(lane>>4)*4+reg. A layout: A[m=lane&15][k=quad*8+j].
__global__ __launch_bounds__(256) void flash_mfma_k(const void* __restrict__ Qp, const void* __restrict__ Kp,
                                                    const int* __restrict__ flagp, float* __restrict__ pacc,
                                                    float* __restrict__ pm, float* __restrict__ pz){
  const int fl = *flagp;
  __shared__ __align__(16) u16 Qs[64][72];
  __shared__ __align__(16) u16 Ks[64][72];
  __shared__ __align__(16) u16 Kt[64][72];   // transposed: Kt[d][kk]
  __shared__ __align__(16) u16 Ps[64][72];
  const int t = threadIdx.x;
  const int w = t >> 6;            // wave 0..3 owns q-rows w*16..w*16+15
  const int lane = t & 63;
  const int col = lane & 15;
  const int quad = lane >> 4;
  const int q0 = blockIdx.x * 64;
  const int kbeg = blockIdx.y * 2048;
  {
    const int r = t >> 2, c0 = (t & 3) * 16;
    if (fl){
      const u16* qp = (const u16*)Qp + (size_t)(q0 + r) * 64 + c0;
      for (int c = 0; c < 16; c++) Qs[r][c0 + c] = qp[c];
    } else {
      const float* qp = (const float*)Qp + (size_t)(q0 + r) * 64 + c0;
      for (int c = 0; c < 16; c++) Qs[r][c0 + c] = f2bf(qp[c]);
    }
  }
  f32x4 accO[4];
  #pragma unroll
  for (int d = 0; d < 4; d++) accO[d] = (f32x4){0.f, 0.f, 0.f, 0.f};
  float m_[4], l_[4];
  #pragma unroll
  for (int i = 0; i < 4; i++){ m_[i] = -1e30f; l_[i] = 0.f; }

  for (int kt = 0; kt < 2048; kt += 64){
    __syncthreads();      // prev PV done before Ks/Kt overwrite
    {
      const int r = t >> 2, c0 = (t & 3) * 16;
      if (fl){
        const u16* kp = (const u16*)Kp + (size_t)(kbeg + kt + r) * 64 + c0;
        for (int c = 0; c < 16; c++){ u16 v = kp[c]; Ks[r][c0+c] = v; Kt[c0+c][r] = v; }
      } else {
        const float* kp = (const float*)Kp + (size_t)(kbeg + kt + r) * 64 + c0;
        for (int c = 0; c < 16; c++){ u16 v = f2bf(kp[c]); Ks[r][c0+c] = v; Kt[c0+c][r] = v; }
      }
    }
    __syncthreads();
    // S = Q K^T  (4 n-tiles of 16 keys)
    f32x4 accS[4];
    #pragma unroll
    for (int nt = 0; nt < 4; nt++) accS[nt] = (f32x4){0.f, 0.f, 0.f, 0.f};
    #pragma unroll
    for (int ks = 0; ks < 2; ks++){
      bf16x8 a = *(const bf16x8*)&Qs[w*16 + col][ks*32 + quad*8];
      #pragma unroll
      for (int nt = 0; nt < 4; nt++){
        bf16x8 b = *(const bf16x8*)&Ks[nt*16 + col][ks*32 + quad*8];
        accS[nt] = __builtin_amdgcn_mfma_f32_16x16x32_bf16(a, b, accS[nt], 0, 0, 0);
      }
    }
    // online softmax per q-row (row = quad*4+i)
    #pragma unroll
    for (int i = 0; i < 4; i++){
      float rm = fmaxf(fmaxf(accS[0][i], accS[1][i]), fmaxf(accS[2][i], accS[3][i]));
      rm = fmaxf(rm, __shfl_xor(rm, 1)); rm = fmaxf(rm, __shfl_xor(rm, 2));
      rm = fmaxf(rm, __shfl_xor(rm, 4)); rm = fmaxf(rm, __shfl_xor(rm, 8));
      const float mn = fmaxf(m_[i], rm);
      const float sc = __expf(m_[i] - mn);
      float p0 = __expf(accS[0][i] - mn), p1 = __expf(accS[1][i] - mn);
      float p2 = __expf(accS[2][i] - mn), p3 = __expf(accS[3][i] - mn);
      float rs = p0 + p1 + p2 + p3;
      rs += __shfl_xor(rs, 1); rs += __shfl_xor(rs, 2); rs += __shfl_xor(rs, 4); rs += __shfl_xor(rs, 8);
      l_[i] = l_[i] * sc + rs; m_[i] = mn;
      #pragma unroll
      for (int d = 0; d < 4; d++) accO[d][i] *= sc;
      Ps[w*16 + quad*4 + i][ 0 + col] = f2bf(p0);
      Ps[w*16 + quad*4 + i][16 + col] = f2bf(p1);
      Ps[w*16 + quad*4 + i][32 + col] = f2bf(p2);
      Ps[w*16 + quad*4 + i][48 + col] = f2bf(p3);
    }
    // O += P V   (wave-local P rows; V^T from Kt)
    #pragma unroll
    for (int ks = 0; ks < 2; ks++){
      bf16x8 a = *(const bf16x8*)&Ps[w*16 + col][ks*32 + quad*8];
      #pragma unroll
      for (int d = 0; d < 4; d++){
        bf16x8 b = *(const bf16x8*)&Kt[d*16 + col][ks*32 + quad*8];
        accO[d] = __builtin_amdgcn_mfma_f32_16x16x32_bf16(a, b, accO[d], 0, 0, 0);
      }
    }
  }
  #pragma unroll
  for (int i = 0; i < 4; i++){
    const int row = q0 + w*16 + quad*4 + i;
    #pragma unroll
    for (int d = 0; d < 4; d++)
      pacc[((size_t)blockIdx.y * NSd + row) * 64 + d*16 + col] = accO[d][i];
    if (col == 0){ pm[blockIdx.y * NSd + row] = m_[i]; pz[blockIdx.y * NSd + row] = l_[i]; }
  }
}

__global__ __launch_bounds__(256) void flash_merge_k(const float* __restrict__ pacc, const float* __restrict__ pm,
                                                     const float* __restrict__ pz, float* __restrict__ outp){
  const int t = threadIdx.x;
  const int r = blockIdx.x * 4 + (t >> 6);
  const int d = t & 63;
  float M = -1e30f;
  #pragma unroll
  for (int s = 0; s < 4; s++) M = fmaxf(M, pm[s * NSd + r]);
  float Zt = 0.f, v = 0.f;
  #pragma unroll
  for (int s = 0; s < 4; s++){
    const float w = __expf(pm[s * NSd + r] - M);
    Zt += pz[s * NSd + r] * w;
    v  += pacc[((size_t)s * NSd + r) * 64 + d] * w;
  }
  outp[(size_t)r * 64 + d] = v / Zt;
}

// ------------------------------- projection ---------------------------------
__global__ __launch_bounds__(256) void proj_k(const void* __restrict__ nbd1, const void* __restrict__ nbd2,
                                              const float* __restrict__ x1a, const float* __restrict__ x2a,
                                              const float* __restrict__ wf, float* __restrict__ hn0,
                                              const int* __restrict__ flagp){
  const int fl = *flagp;
  __shared__ float At[64][65], Bt[64][65];
  const int t = threadIdx.x, tx = t & 15, ty = t >> 4;
  const int m0 = blockIdx.x * 64;
  float acc[4][4] = {{0.f}};
  for (int kt = 0; kt < 256; kt += 64){
    __syncthreads();
    {
      const int i = t >> 2, c0 = (t & 3) * 16;
      const int mrow = m0 + i;
      const int side = mrow < NSd;
      const int mr = side ? mrow : mrow - NSd;
      const void* nb = side ? nbd1 : nbd2;
      const float* xa = side ? x1a : x2a;
      const int seg = kt >> 6;
      for (int c = 0; c < 16; c++){
        const int kk = c0 + c;
        const float nv = ldin(nb, (size_t)mr * 64 + kk, fl);
        const float av = xa[(size_t)mr * 64 + kk];
        At[i][kk] = (seg == 0) ? nv : (seg == 1) ? av : (seg == 2) ? (nv - av) : (nv * av);
      }
      const int kk = t >> 2;
      for (int c = 0; c < 16; c++) Bt[kk][c0 + c] = wf[WO_PROJ + (kt + kk) * 64 + c0 + c];
    }
    __syncthreads();
    #pragma unroll
    for (int k = 0; k < 64; k++){
      float a0 = At[ty*4+0][k], a1 = At[ty*4+1][k], a2 = At[ty*4+2][k], a3 = At[ty*4+3][k];
      float b0 = Bt[k][tx*4+0], b1 = Bt[k][tx*4+1], b2 = Bt[k][tx*4+2], b3 = Bt[k][tx*4+3];
      acc[0][0] = fmaf(a0,b0,acc[0][0]); acc[0][1] = fmaf(a0,b1,acc[0][1]); acc[0][2] = fmaf(a0,b2,acc[0][2]); acc[0][3] = fmaf(a0,b3,acc[0][3]);
      acc[1][0] = fmaf(a1,b0,acc[1][0]); acc[1][1] = fmaf(a1,b1,acc[1][1]); acc[1][2] = fmaf(a1,b2,acc[1][2]); acc[1][3] = fmaf(a1,b3,acc[1][3]);
      acc[2][0] = fmaf(a2,b0,acc[2][0]); acc[2][1] = fmaf(a2,b1,acc[2][1]); acc[2][2] = fmaf(a2,b2,acc[2][2]); acc[2][3] = fmaf(a2,b3,acc[2][3]);
      acc[3][0] = fmaf(a3,b0,acc[3][0]); acc[3][1] = fmaf(a3,b1,acc[3][1]); acc[3][2] = fmaf(a3,b2,acc[3][2]); acc[3][3] = fmaf(a3,b3,acc[3][3]);
    }
  }
  #pragma unroll
  for (int i = 0; i < 4; i++)
    #pragma unroll
    for (int j = 0; j < 4; j++)
      hn0[(size_t)(m0 + ty*4 + i) * 64 + tx*4 + j] = fmaxf(acc[i][j], 0.f);
}

// ---------------------- per-node a1/a2 (block per node) ---------------------
template<int K>
__global__ __launch_bounds__(256) void an_node_k(const float* __restrict__ in, const float* __restrict__ wc,
                                                 float* __restrict__ an){
  __shared__ float row[K];
  const int n = blockIdx.x;
  const int t = threadIdx.x;
  for (int c = t; c < K; c += 256) row[c] = in[(size_t)n * K + c];
  __syncthreads();
  const int o = t >> 4, sub = t & 15;
  constexpr int CH = K / 16;
  float acc = 0.f;
  for (int c = 0; c < CH; c++)
    acc = fmaf(row[sub + 16*c], wc[o*K + sub + 16*c], acc);
  acc += __shfl_xor(acc, 1); acc += __shfl_xor(acc, 2);
  acc += __shfl_xor(acc, 4); acc += __shfl_xor(acc, 8);
  if (sub == 0) an[n * 16 + o] = acc;
}

// ------------------------------ small kernels -------------------------------
__global__ __launch_bounds__(256) void u_k(const void* __restrict__ ebd, const float* __restrict__ hn0,
                                           const int* __restrict__ src, float* __restrict__ U,
                                           const int* __restrict__ flagp){
  const int fl = *flagp;
  const int id = blockIdx.x * 256 + threadIdx.x;
  const int e = id >> 6, d = id & 63;
  U[id] = ldin(ebd, id, fl) + hn0[(size_t)src[e] * 64 + d];
}

__global__ __launch_bounds__(256) void s1_k(const void* __restrict__ ebd, const float* __restrict__ cb,
                                            const int* __restrict__ src, const int* __restrict__ dst,
                                            const float* __restrict__ an, float* __restrict__ S,
                                            const int* __restrict__ flagp){
  const int fl = *flagp;
  const int id = blockIdx.x * 256 + threadIdx.x;
  const int e = id >> 3, h = id & 7;
  float a3 = 0.f;
  const float* w = cb + CB_WE1 + h * 64;
  for (int d = 0; d < 64; d++) a3 = fmaf(ldin(ebd, (size_t)e * 64 + d, fl), w[d], a3);
  const float a = an[src[e] * 16 + h] + a3 + an[dst[e] * 16 + 8 + h];
  S[id] = leaky(a);
}

// segment softmax stats + alpha write, one (n,h) wave
__global__ __launch_bounds__(256) void segalpha_k(const float* __restrict__ S, const int* __restrict__ rp,
                                                  const int* __restrict__ cidx, float* __restrict__ AL){
  const int w = blockIdx.x * 4 + (threadIdx.x >> 6);
  const int lane = threadIdx.x & 63;
  const int n = w >> 3, h = w & 7;
  const int beg = rp[n], end = rp[n + 1];
  float m = -1e30f, z = 0.f;
  for (int base = beg; base < end; base += 64){
    const int idx = base + lane;
    float v = -1e30f, cc = 0.f;
    if (idx < end){ v = S[(size_t)cidx[idx] * 8 + h]; cc = 1.f; }
    lse_merge(m, z, v, cc);
  }
  #pragma unroll
  for (int off = 32; off; off >>= 1){
    float om = __shfl_xor(m, off), oz = __shfl_xor(z, off);
    lse_merge(m, z, om, oz);
  }
  const float rz = 1.f / fmaxf(z, 1e-9f);
  for (int base = beg; base < end; base += 64){
    const int idx = base + lane;
    if (idx < end){
      const int e = cidx[idx];
      AL[(size_t)e * 8 + h] = __expf(S[(size_t)e * 8 + h] - m) * rz;
    }
  }
}

// g1[n,h,d] — block per node, 4 h-pairs per thread-slice
__global__ __launch_bounds__(256) void g1b_k(const float* __restrict__ AL, const float* __restrict__ U,
                                             const int* __restrict__ rp, const int* __restrict__ cidx,
                                             float* __restrict__ G1){
  const int n = blockIdx.x;
  const int t = threadIdx.x;
  const int d = t & 63, hh = t >> 6;   // h = hh, hh+4
  const int beg = rp[n], end = rp[n + 1];
  float a0 = 0.f, a1 = 0.f;
  for (int idx = beg; idx < end; idx++){
    const int e = cidx[idx];
    const float uv = U[(size_t)e * 64 + d];
    a0 = fmaf(AL[(size_t)e * 8 + hh],     uv, a0);
    a1 = fmaf(AL[(size_t)e * 8 + hh + 4], uv, a1);
  }
  G1[(size_t)(n * 8 + hh)     * 64 + d] = a0;
  G1[(size_t)(n * 8 + hh + 4) * 64 + d] = a1;
}

__global__ __launch_bounds__(256) void nft1_k(const float* __restrict__ G1, const float* __restrict__ wf,
                                              float* __restrict__ HNA){
  const int id = blockIdx.x * 256 + threadIdx.x;
  const int n = id >> 9, c = id & 511, h = c >> 6;
  const float* g = G1 + (size_t)(n * 8 + h) * 64;
  float acc = 0.f;
  for (int d = 0; d < 64; d++) acc = fmaf(g[d], wf[WO_W1 + d * 512 + c], acc);
  HNA[id] = eluf(acc);
}

// layer-2 scores: S2[e,h2] = leaky(a1[src] + f2[e]·WE2[h2] + a2[dst]),
// f2 = elu(alpha1 ⊙ (U@W1)) computed in registers, never stored.
__global__ __launch_bounds__(256) void s2new_k(const float* __restrict__ U, const float* __restrict__ AL1,
                                               const float* __restrict__ wf, const float* __restrict__ cb,
                                               const int* __restrict__ src, const int* __restrict__ dst,
                                               const float* __restrict__ AN, float* __restrict__ S){
  __shared__ float Us[64][68];
  __shared__ float Ws[64][68];
  __shared__ float We[8][64];
  const int t = threadIdx.x, tx = t & 15, ty = t >> 4;
  const int e0 = blockIdx.x * 64;
  {
    const int r = t >> 2, c0 = (t & 3) * 16;
    const float* up = U + (size_t)(e0 + r) * 64 + c0;
    for (int c = 0; c < 16; c++) Us[r][c0 + c] = up[c];
  }
  float a3[4][8] = {{0.f}};
  for (int h = 0; h < 8; h++){
    __syncthreads();
    {
      const int d = t >> 2, c0 = (t & 3) * 16;
      const float* wp = wf + WO_W1 + d * 512 + h * 64 + c0;
      for (int c = 0; c < 16; c++) Ws[d][c0 + c] = wp[c];
    }
    if (t < 128){
      const int h2 = t >> 4, cc = (t & 15) * 4;
      for (int c = 0; c < 4; c++) We[h2][cc + c] = cb[CB_WE2 + h2 * 512 + h * 64 + cc + c];
    }
    __syncthreads();
    float sv[4][4] = {{0.f}};
    #pragma unroll
    for (int k = 0; k < 64; k++){
      float a0 = Us[ty*4+0][k], a1 = Us[ty*4+1][k], a2 = Us[ty*4+2][k], aa3 = Us[ty*4+3][k];
      float b0 = Ws[k][tx*4+0], b1 = Ws[k][tx*4+1], b2 = Ws[k][tx*4+2], b3 = Ws[k][tx*4+3];
      sv[0][0] = fmaf(a0,b0,sv[0][0]); sv[0][1] = fmaf(a0,b1,sv[0][1]); sv[0][2] = fmaf(a0,b2,sv[0][2]); sv[0][3] = fmaf(a0,b3,sv[0][3]);
      sv[1][0] = fmaf(a1,b0,sv[1][0]); sv[1][1] = fmaf(a1,b1,sv[1][1]); sv[1][2] = fmaf(a1,b2,sv[1][2]); sv[1][3] = fmaf(a1,b3,sv[1][3]);
      sv[2][0] = fmaf(a2,b0,sv[2][0]); sv[2][1] = fmaf(a2,b1,sv[2][1]); sv[2][2] = fmaf(a2,b2,sv[2][2]); sv[2][3] = fmaf(a2,b3,sv[2][3]);
      sv[3][0] = fmaf(aa3,b0,sv[3][0]); sv[3][1] = fmaf(aa3,b1,sv[3][1]); sv[3][2] = fmaf(aa3,b2,sv[3][2]); sv[3][3] = fmaf(aa3,b3,sv[3][3]);
    }
    #pragma unroll
    for (int i = 0; i < 4; i++){
      const float al = AL1[(size_t)(e0 + ty*4 + i) * 8 + h];
      #pragma unroll
      for (int j = 0; j < 4; j++){
        const float f2 = eluf(al * sv[i][j]);
        const int c = tx*4 + j;
        #pragma unroll
        for (int h2 = 0; h2 < 8; h2++) a3[i][h2] = fmaf(f2, We[h2][c], a3[i][h2]);
      }
    }
  }
  #pragma unroll
  for (int i = 0; i < 4; i++)
    #pragma unroll
    for (int h2 = 0; h2 < 8; h2++){
      float v = a3[i][h2];
      v += __shfl_xor(v, 1); v += __shfl_xor(v, 2);
      v += __shfl_xor(v, 4); v += __shfl_xor(v, 8);
      a3[i][h2] = v;
    }
  if (tx == 0){
    #pragma unroll
    for (int i = 0; i < 4; i++){
      const int e = e0 + ty*4 + i;
      const int se = src[e], de = dst[e];
      #pragma unroll
      for (int h2 = 0; h2 < 8; h2++)
        S[(size_t)e * 8 + h2] = leaky(AN[se * 16 + h2] + a3[i][h2] + AN[de * 16 + 8 + h2]);
    }
  }
}

// slice y (NS=8): y[ep,c] = elu(alpha1·(U@W1)) + hnA[src], bf16
__global__ __launch_bounds__(256) void y_k(const float* __restrict__ U, const float* __restrict__ AL1,
                                           const float* __restrict__ HNA, const float* __restrict__ wf,
                                           const int* __restrict__ src, const int* __restrict__ cidx,
                                           u16* __restrict__ Y, const int s){
  __shared__ float Us[64][68], Ws[64][68];
  __shared__ int Es[64], Ss[64];
  const int t = threadIdx.x, tx = t & 15, ty = t >> 4;
  const int ep0 = s * 16384 + blockIdx.x * 64;
  if (t < 64){ const int e = cidx[ep0 + t]; Es[t] = e; Ss[t] = src[e]; }
  __syncthreads();
  {
    const int i = t >> 2, c0 = (t & 3) * 16;
    const float* up = U + (size_t)Es[i] * 64 + c0;
    for (int c = 0; c < 16; c++) Us[i][c0 + c] = up[c];
  }
  for (int h = 0; h < 8; h++){
    __syncthreads();
    {
      const int d = t >> 2, c0 = (t & 3) * 16;
      const float* wp = wf + WO_W1 + d * 512 + h * 64 + c0;
      for (int c = 0; c < 16; c++) Ws[d][c0 + c] = wp[c];
    }
    __syncthreads();
    float sv[4][4] = {{0.f}};
    #pragma unroll
    for (int k = 0; k < 64; k++){
      float a0 = Us[ty*4+0][k], a1 = Us[ty*4+1][k], a2 = Us[ty*4+2][k], a3 = Us[ty*4+3][k];
      float b0 = Ws[k][tx*4+0], b1 = Ws[k][tx*4+1], b2 = Ws[k][tx*4+2], b3 = Ws[k][tx*4+3];
      sv[0][0] = fmaf(a0,b0,sv[0][0]); sv[0][1] = fmaf(a0,b1,sv[0][1]); sv[0][2] = fmaf(a0,b2,sv[0][2]); sv[0][3] = fmaf(a0,b3,sv[0][3]);
      sv[1][0] = fmaf(a1,b0,sv[1][0]); sv[1][1] = fmaf(a1,b1,sv[1][1]); sv[1][2] = fmaf(a1,b2,sv[1][2]); sv[1][3] = fmaf(a1,b3,sv[1][3]);
      sv[2][0] = fmaf(a2,b0,sv[2][0]); sv[2][1] = fmaf(a2,b1,sv[2][1]); sv[2][2] = fmaf(a2,b2,sv[2][2]); sv[2][3] = fmaf(a2,b3,sv[2][3]);
      sv[3][0] = fmaf(a3,b0,sv[3][0]); sv[3][1] = fmaf(a3,b1,sv[3][1]); sv[3][2] = fmaf(a3,b2,sv[3][2]); sv[3][3] = fmaf(a3,b3,sv[3][3]);
    }
    #pragma unroll
    for (int i = 0; i < 4; i++){
      const int r = ty*4 + i;
      const float al = AL1[(size_t)Es[r] * 8 + h];
      const float* ha = HNA + (size_t)Ss[r] * 512 + h * 64 + tx*4;
      #pragma unroll
      for (int j = 0; j < 4; j++){
        const float v = eluf(al * sv[i][j]) + ha[j];
        Y[(size_t)(blockIdx.x * 64 + r) * 512 + h * 64 + tx*4 + j] = f2bf(v);
      }
    }
  }
}

// slice g2 (bf16 out): g2[nl,h,c] = sum alpha2[e,h]*y[ep,c]
__global__ __launch_bounds__(256) void g2_k(const float* __restrict__ AL2, const u16* __restrict__ Y,
                                            const int* __restrict__ rp, const int* __restrict__ cidx,
                                            u16* __restrict__ G2, const int s){
  const int t = threadIdx.x;
  const int nl = blockIdx.x;              // 0..2047
  const int n = s * 2048 + nl;
  const int d4 = (t & 127) * 4;
  const int hh = (t >> 7) * 4;
  const int beg = rp[n], end = rp[n + 1];
  const int base = s * 16384;
  float acc[4][4] = {{0.f}};
  for (int pos = beg; pos < end; pos++){
    const int e = cidx[pos];
    const int epl = pos - base;
    const float4 a4 = *(const float4*)(AL2 + (size_t)e * 8 + hh);
    const ushort4 yv = *(const ushort4*)(Y + (size_t)epl * 512 + d4);
    const float y0 = bf2f(yv.x), y1 = bf2f(yv.y), y2 = bf2f(yv.z), y3 = bf2f(yv.w);
    acc[0][0] = fmaf(a4.x, y0, acc[0][0]); acc[0][1] = fmaf(a4.x, y1, acc[0][1]); acc[0][2] = fmaf(a4.x, y2, acc[0][2]); acc[0][3] = fmaf(a4.x, y3, acc[0][3]);
    acc[1][0] = fmaf(a4.y, y0, acc[1][0]); acc[1][1] = fmaf(a4.y, y1, acc[1][1]); acc[1][2] = fmaf(a4.y, y2, acc[1][2]); acc[1][3] = fmaf(a4.y, y3, acc[1][3]);
    acc[2][0] = fmaf(a4.z, y0, acc[2][0]); acc[2][1] = fmaf(a4.z, y1, acc[2][1]); acc[2][2] = fmaf(a4.z, y2, acc[2][2]); acc[2][3] = fmaf(a4.z, y3, acc[2][3]);
    acc[3][0] = fmaf(a4.w, y0, acc[3][0]); acc[3][1] = fmaf(a4.w, y1, acc[3][1]); acc[3][2] = fmaf(a4.w, y2, acc[3][2]); acc[3][3] = fmaf(a4.w, y3, acc[3][3]);
  }
  #pragma unroll
  for (int hi = 0; hi < 4; hi++)
    #pragma unroll
    for (int di = 0; di < 4; di++)
      G2[((size_t)nl * 8 + hh + hi) * 512 + d4 + di] = f2bf(acc[hi][di]);
}

// slice nft2: hnB[n, h*64+d'] = elu( sum_c g2[nl,h,c] * W2[c, h*64+d'] )
__global__ __launch_bounds__(256) void nft2_k(const u16* __restrict__ G2, const float* __restrict__ wf,
                                              float* __restrict__ HNB, const int s){
  __shared__ float At[64][65], Bt[64][65];
  const int t = threadIdx.x, tx = t & 15, ty = t >> 4;
  const int h = blockIdx.y;
  const int nl0 = blockIdx.x * 64;
  float acc[4][4] = {{0.f}};
  for (int kt = 0; kt < 512; kt += 64){
    __syncthreads();
    {
      const int i = t >> 2, c0 = (t & 3) * 16;
      const u16* gp = G2 + ((size_t)(nl0 + i) * 8 + h) * 512 + kt + c0;
      for (int c = 0; c < 16; c++) At[i][c0 + c] = bf2f(gp[c]);
      const int kk = t >> 2;
      const float* wp = wf + WO_W2 + (size_t)(kt + kk) * 512 + h * 64 + c0;
      for (int c = 0; c < 16; c++) Bt[kk][c0 + c] = wp[c];
    }
    __syncthreads();
    #pragma unroll
    for (int k = 0; k < 64; k++){
      float a0 = At[ty*4+0][k], a1 = At[ty*4+1][k], a2 = At[ty*4+2][k], a3 = At[ty*4+3][k];
      float b0 = Bt[k][tx*4+0], b1 = Bt[k][tx*4+1], b2 = Bt[k][tx*4+2], b3 = Bt[k][tx*4+3];
      acc[0][0] = fmaf(a0,b0,acc[0][0]); acc[0][1] = fmaf(a0,b1,acc[0][1]); acc[0][2] = fmaf(a0,b2,acc[0][2]); acc[0][3] = fmaf(a0,b3,acc[0][3]);
      acc[1][0] = fmaf(a1,b0,acc[1][0]); acc[1][1] = fmaf(a1,b1,acc[1][1]); acc[1][2] = fmaf(a1,b2,acc[1][2]); acc[1][3] = fmaf(a1,b3,acc[1][3]);
      acc[2][0] = fmaf(a2,b0,acc[2][0]); acc[2][1] = fmaf(a2,b1,acc[2][1]); acc[2][2] = fmaf(a2,b2,acc[2][2]); acc[2][3] = fmaf(a2,b3,acc[2][3]);
      acc[3][0] = fmaf(a3,b0,acc[3][0]); acc[3][1] = fmaf(a3,b1,acc[3][1]); acc[3][2] = fmaf(a3,b2,acc[3][2]); acc[3][3] = fmaf(a3,b3,acc[3][3]);
    }
  }
  #pragma unroll
  for (int i = 0; i < 4; i++)
    #pragma unroll
    for (int j = 0; j < 4; j++)
      HNB[(size_t)(s * 2048 + nl0 + ty*4 + i) * 512 + h * 64 + tx*4 + j] = eluf(acc[i][j]);
}

// ---------------------------------- CSR -------------------------------------
__global__ __launch_bounds__(256) void hist_k(const int* __restrict__ dst, int* __restrict__ deg){
  const int e = blockIdx.x * 256 + threadIdx.x;
  if (e < NEd) atomicAdd(&deg[dst[e]], 1);
}
__global__ __launch_bounds__(256) void scan_k(const int* __restrict__ deg, int* __restrict__ rp,
                                              int* __restrict__ fill){
  __shared__ int ps[257];
  const int t = threadIdx.x;
  const int base = t * 64;
  int s = 0;
  for (int i = 0; i < 64; i++) s += deg[base + i];
  ps[t + 1] = s;
  if (t == 0) ps[0] = 0;
  __syncthreads();
  if (t == 0) for (int i = 1; i <= 256; i++) ps[i] += ps[i - 1];
  __syncthreads();
  int off = ps[t];
  for (int i = 0; i < 64; i++){ rp[base + i] = off; fill[base + i] = off; off += deg[base + i]; }
  if (t == 255) rp[NNd] = off;
}
__global__ __launch_bounds__(256) void scatter_k(const int* __restrict__ dst, int* __restrict__ fill,
                                                 int* __restrict__ cidx){
  const int e = blockIdx.x * 256 + threadIdx.x;
  if (e < NEd){ int pos = atomicAdd(&fill[dst[e]], 1); cidx[pos] = e; }
}

// ------------------------------- readout ------------------------------------
__global__ __launch_bounds__(256) void mean_k(const float* __restrict__ HNB, float* __restrict__ xcat){
  const int sg = blockIdx.x;   // 0..31
  const int t = threadIdx.x;
  const int g = (sg < 16) ? sg : sg - 16;
  const int half = (sg < 16) ? 0 : 1;
  for (int c = t; c < 512; c += 256){
    float s = 0.f;
    const float* base = HNB + (size_t)sg * 512 * 512 + c;
    for (int n = 0; n < 512; n++) s += base[(size_t)n * 512];
    xcat[g * 1024 + half * 512 + c] = s * (1.f / 512.f);
  }
}

__global__ __launch_bounds__(1024) void head_k(float* __restrict__ xcat, const float* __restrict__ wf,
                                               void* __restrict__ outp, const int* __restrict__ flagp){
  __shared__ float y1[16][64];
  __shared__ float y2[16][64];
  __shared__ float mu2s[64], sc2s[64];
  const int t = threadIdx.x;
  {
    float mu = 0.f;
    #pragma unroll
    for (int g = 0; g < 16; g++) mu += xcat[g * 1024 + t];
    mu *= (1.f / 16.f);
    float var = 0.f;
    #pragma unroll
    for (int g = 0; g < 16; g++){ float d = xcat[g * 1024 + t] - mu; var += d * d; }
    var *= (1.f / 16.f);
    const float sc = rsqrtf(var + 1e-5f) * wf[WO_B1G + t];
    const float sh = wf[WO_B1B + t] - mu * sc;
    #pragma unroll
    for (int g = 0; g < 16; g++) xcat[g * 1024 + t] = xcat[g * 1024 + t] * sc + sh;
  }
  __syncthreads();
  {
    const int gg = t >> 6, c = t & 63;
    float acc = wf[WO_F1B + c];
    for (int k = 0; k < 1024; k++) acc = fmaf(xcat[gg * 1024 + k], wf[WO_F1W + k * 64 + c], acc);
    y1[gg][c] = fmaxf(acc, 0.f);
  }
  __syncthreads();
  if (t < 64){
    float mu = 0.f;
    #pragma unroll
    for (int g = 0; g < 16; g++) mu += y1[g][t];
    mu *= (1.f / 16.f);
    float var = 0.f;
    #pragma unroll
    for (int g = 0; g < 16; g++){ float d = y1[g][t] - mu; var += d * d; }
    var *= (1.f / 16.f);
    mu2s[t] = mu; sc2s[t] = rsqrtf(var + 1e-5f) * wf[WO_B2G + t];
  }
  __syncthreads();
  {
    const int gg = t >> 6, c = t & 63;
    y2[gg][c] = (y1[gg][c] - mu2s[c]) * sc2s[c] + wf[WO_B2B + c];
  }
  __syncthreads();
  if (t < 48){
    const int gg = t / 3, c = t % 3;
    float acc = wf[WO_F2B + c];
    #pragma unroll
    for (int k = 0; k < 64; k++) acc = fmaf(y2[gg][k], wf[WO_F2W + k * 3 + c], acc);
    if (*flagp) ((u16*)outp)[t] = f2bf(acc);
    else        ((float*)outp)[t] = acc;
  }
}

// --------------------------------- launch -----------------------------------
extern "C" void kernel_launch(void* const* d_in, const int* in_sizes, int n_in,
                              void* d_out, int out_size, void* d_ws, size_t ws_size,
                              hipStream_t stream) {
  (void)in_sizes; (void)n_in; (void)out_size;
  if (ws_size < WS_NEED) return;

  const int* src = (const int*)d_in[3];
  const int* dst = (const int*)d_in[4];
  char* w = (char*)d_ws;

  float* wf   = (float*)(w + OFF_WF);
  float* cb   = (float*)(w + OFF_CB);
  float* U    = (float*)(w + OFF_U);
  float* AL1  = (float*)(w + OFF_AL1);
  float* AL2  = (float*)(w + OFF_AL2);
  float* HNA  = (float*)(w + OFF_HNA);
  int*   deg  = (int*)(w + OFF_DEG);
  int*   rp   = (int*)(w + OFF_RP);
  int*   fill = (int*)(w + OFF_FILL);
  int*   cidx = (int*)(w + OFF_CIDX);
  float* rbig = (float*)(w + OFF_RBIG);
  float* xcat = (float*)(w + OFF_XCAT);
  int*   flag = (int*)(w + OFF_FLAG);

  float* x1a  = (float*)(w + OFF_T + T_X1A);
  float* x2a  = (float*)(w + OFF_T + T_X2A);
  float* hn0  = (float*)(w + OFF_T + T_HN0);
  float* AN   = (float*)(w + OFF_T + T_AN);
  float* S    = (float*)(w + OFF_T + T_S);
  u16*   Y    = (u16*)(w + OFF_T + T_Y);
  u16*   G2   = (u16*)(w + OFF_T + T_G2);

  float* pacc = rbig;
  float* pm   = (float*)(w + OFF_RBIG + 8388608);
  float* pz   = (float*)(w + OFF_RBIG + 8519680);
  float* G1   = rbig;           // after flash merge
  float* HNB  = rbig;           // after nft1

  // 0. detect + weights + combos
  detect_k<<<1, 256, 0, stream>>>((const u16*)d_in[0], flag);
  P17 ps;
  for (int i = 0; i < 17; i++) ps.p[i] = d_in[6 + i];
  convw_k<<<(WO_END + 255) / 256, 256, 0, stream>>>(ps, wf, flag);
  combos_k<<<(CB_END + 255) / 256, 256, 0, stream>>>(wf, cb);

  // 1. CSR over dst
  hipMemsetAsync(deg, 0, NNd * sizeof(int), stream);
  hist_k<<<NEd / 256, 256, 0, stream>>>(dst, deg);
  scan_k<<<1, 256, 0, stream>>>(deg, rp, fill);
  scatter_k<<<NEd / 256, 256, 0, stream>>>(dst, fill, cidx);

  // 2. alignment (MFMA flash)
  flash_mfma_k<<<dim3(128, 4), 256, 0, stream>>>(d_in[0], d_in[1], flag, pacc, pm, pz);
  flash_merge_k<<<NSd / 4, 256, 0, stream>>>(pacc, pm, pz, x1a);
  flash_mfma_k<<<dim3(128, 4), 256, 0, stream>>>(d_in[1], d_in[0], flag, pacc, pm, pz);
  flash_merge_k<<<NSd / 4, 256, 0, stream>>>(pacc, pm, pz, x2a);

  // 3. projection
  proj_k<<<NNd / 64, 256, 0, stream>>>(d_in[0], d_in[1], x1a, x2a, wf, hn0, flag);

  // 4. GAT layer 1
  an_node_k<64><<<NNd, 256, 0, stream>>>(hn0, cb + CB_WC1, AN);
  u_k<<<NEd * 64 / 256, 256, 0, stream>>>(d_in[2], hn0, src, U, flag);
  s1_k<<<NEd * 8 / 256, 256, 0, stream>>>(d_in[2], cb, src, dst, AN, S, flag);
  segalpha_k<<<NNd * 8 / 4, 256, 0, stream>>>(S, rp, cidx, AL1);
  g1b_k<<<NNd, 256, 0, stream>>>(AL1, U, rp, cidx, G1);
  nft1_k<<<NNd * 512 / 256, 256, 0, stream>>>(G1, wf, HNA);

  // 5. GAT layer 2 scores (no eft2 materialization, no recompute duplication)
  an_node_k<512><<<NNd, 256, 0, stream>>>(HNA, cb + CB_WC2, AN);
  s2new_k<<<NEd / 64, 256, 0, stream>>>(U, AL1, wf, cb, src, dst, AN, S);
  segalpha_k<<<NNd * 8 / 4, 256, 0, stream>>>(S, rp, cidx, AL2);

  // 6. layer-2 aggregation: 8 slices × (y, g2, nft2)
  for (int s = 0; s < 8; s++){
    y_k<<<256, 256, 0, stream>>>(U, AL1, HNA, wf, src, cidx, Y, s);
    g2_k<<<2048, 256, 0, stream>>>(AL2, Y, rp, cidx, G2, s);
    nft2_k<<<dim3(32, 8), 256, 0, stream>>>(G2, wf, HNB, s);
  }

  // 7. readout
  mean_k<<<32, 256, 0, stream>>>(HNB, xcat);
  head_k<<<1, 1024, 0, stream>>>(xcat, wf, d_out, flag);
}

// Round 4
// 2346.588 us; speedup vs baseline: 2.0236x; 1.3451x over previous
//
#include <hip/hip_runtime.h>

// GATClassifier on MI355X — round 4: s2new (spilling, 1065us) eliminated via
// score-from-Y algebra (WC2' = W2*(al2-ae2) combo); slice-local layer 2:
// y -> s2y -> segalpha2(pos,in-place) -> g2(pos-alpha) -> nft2(bf16 out).
// nft1 tiled; HNB bf16. ws 144.98 MB (proven safe).

#define NSd 8192
#define NNd 16384
#define NEd 131072

typedef unsigned short u16;
typedef unsigned int   u32;
typedef short bf16x8 __attribute__((ext_vector_type(8)));
typedef float f32x4  __attribute__((ext_vector_type(4)));

__device__ __forceinline__ float bf2f(u16 u){ return __uint_as_float(((u32)u) << 16); }
__device__ __forceinline__ u16 f2bf(float f){
  u32 u = __float_as_uint(f);
  u += 0x7fffu + ((u >> 16) & 1u);
  return (u16)(u >> 16);
}
__device__ __forceinline__ float eluf(float x){ return x > 0.f ? x : expm1f(x); }
__device__ __forceinline__ float leaky(float x){ return x > 0.f ? x : 0.2f * x; }
__device__ __forceinline__ float ldin(const void* p, size_t i, int fl){
  return fl ? bf2f(((const u16*)p)[i]) : ((const float*)p)[i];
}
__device__ __forceinline__ void lse_merge(float& m, float& z, float om, float oz){
  float M = fmaxf(m, om);
  z = z * __expf(m - M) + oz * __expf(om - M);
  m = M;
}

// ------------------------- workspace layout (bytes) -------------------------
static constexpr size_t OFF_WF   = 0;            // 382339 f32 weights
static constexpr size_t OFF_CB   = 1529600;      // 13824 f32 combos
static constexpr size_t OFF_U    = 1584896;      // 131072*64 f32
static constexpr size_t OFF_AL1  = 35139328;     // 131072*8 f32 (edge-id idx)
static constexpr size_t OFF_SA   = 39333632;     // 131072*8 f32 S2/alpha2 by CSR pos
static constexpr size_t OFF_HNA  = 43527936;     // 16384*512 f32
static constexpr size_t OFF_DEG  = 77082368;     // 16384 int
static constexpr size_t OFF_RP   = 77147904;     // 16385 int (padded)
static constexpr size_t OFF_FILL = 77213696;
static constexpr size_t OFF_CIDX = 77279232;     // 131072 int
static constexpr size_t OFF_RBIG = 77803520;     // 33.5MB: flash | G1 | HNB16+AN2
static constexpr size_t OFF_T    = 111357952;    // 32MB union region
static constexpr size_t OFF_XCAT = 144912384;
static constexpr size_t OFF_FLAG = 144977920;
static constexpr size_t WS_NEED  = 144978176;

// T-union (early phase)
static constexpr size_t T_X1A = 0;               // 8192*64 f32
static constexpr size_t T_X2A = 2097152;
static constexpr size_t T_HN0 = 4194304;         // 16384*64 f32
static constexpr size_t T_AN1 = 8388608;         // 16384*16 f32
static constexpr size_t T_S   = 9437184;         // 131072*8 f32 (layer-1, edge-id)
// T-union (slice phase, NS=8)
static constexpr size_t T_Y   = 0;               // 16384*512 bf16
static constexpr size_t T_G2  = 16777216;        // 2048*8*512 bf16
// RBIG sub-offsets
static constexpr size_t R_PM  = 8388608;         // flash pm (after 8MB pacc)
static constexpr size_t R_PZ  = 8519680;
static constexpr size_t R_AN2 = 16777216;        // 16384*16 f32 (after G1 dead; above HNB16)

// weight offsets (floats within OFF_WF)
static constexpr int WO_PROJ = 0,      WO_W1 = 16384;
static constexpr int WO_AL1 = 49152,   WO_AR1 = 49664,  WO_AE1 = 50176;
static constexpr int WO_W2  = 50688;
static constexpr int WO_AL2 = 312832,  WO_AR2 = 313344, WO_AE2 = 313856;
static constexpr int WO_B1G = 314368,  WO_B1B = 315392;
static constexpr int WO_F1W = 316416,  WO_F1B = 381952;
static constexpr int WO_B2G = 382016,  WO_B2B = 382080;
static constexpr int WO_F2W = 382144,  WO_F2B = 382336;
static constexpr int WO_END = 382339;

// combo offsets (floats within OFF_CB)
static constexpr int CB_WC1 = 0;      // [16][64]
static constexpr int CB_WE1 = 1024;   // [8][64]
static constexpr int CB_WC2 = 1536;   // [16][512]  (rows 0..8 = W2*(al2-ae2)!)
static constexpr int CB_WE2 = 9728;   // [8][512]
static constexpr int CB_END = 13824;

// ------------------------------- dtype detect -------------------------------
__global__ __launch_bounds__(256) void detect_k(const u16* __restrict__ p, int* __restrict__ flag){
  __shared__ int bad;
  if (threadIdx.x == 0) bad = 0;
  __syncthreads();
  int b = 0;
  for (int i = threadIdx.x; i < 1024; i += 256){
    float f = bf2f(p[i]);
    if (!(fabsf(f) <= 100.f)) b++;
  }
  atomicAdd(&bad, b);
  __syncthreads();
  if (threadIdx.x == 0) *flag = (bad == 0) ? 1 : 0;
}

struct P17 { const void* p[17]; };

__global__ __launch_bounds__(256) void convw_k(P17 ps, float* __restrict__ wf, const int* __restrict__ flagp){
  const int i = blockIdx.x * 256 + threadIdx.x;
  if (i >= WO_END) return;
  const int fl = *flagp;
  const int ends[17] = {16384,49152,49664,50176,50688,312832,313344,313856,314368,
                        315392,316416,381952,382016,382080,382144,382336,382339};
  int seg = 0;
  while (i >= ends[seg]) seg++;
  const int start = seg ? ends[seg-1] : 0;
  wf[i] = ldin(ps.p[seg], i - start, fl);
}

__global__ __launch_bounds__(256) void combos_k(const float* __restrict__ wf, float* __restrict__ cb){
  const int i = blockIdx.x * 256 + threadIdx.x;
  if (i >= CB_END) return;
  float acc = 0.f;
  if (i < 1024){
    const int o = i >> 6, d = i & 63, h = o & 7;
    const float* a = wf + ((o >> 3) ? WO_AR1 : WO_AL1) + h * 64;
    for (int dp = 0; dp < 64; dp++) acc += wf[WO_W1 + d * 512 + h * 64 + dp] * a[dp];
    cb[CB_WC1 + i] = acc;
  } else if (i < 1536){
    const int j = i - 1024, h = j >> 6, d = j & 63;
    for (int dp = 0; dp < 64; dp++) acc += wf[WO_W1 + d * 512 + h * 64 + dp] * wf[WO_AE1 + h * 64 + dp];
    cb[CB_WE1 + j] = acc;
  } else if (i < 9728){
    // rows 0..7: W2*(al2-ae2)  (folds -anE[src] into the a1 term); rows 8..15: W2*ar2
    const int j = i - 1536, o = j >> 9, c = j & 511, h = o & 7;
    for (int dp = 0; dp < 64; dp++){
      const float av = (o >> 3) ? wf[WO_AR2 + h * 64 + dp]
                                : (wf[WO_AL2 + h * 64 + dp] - wf[WO_AE2 + h * 64 + dp]);
      acc += wf[WO_W2 + c * 512 + h * 64 + dp] * av;
    }
    cb[CB_WC2 + j] = acc;
  } else {
    const int j = i - 9728, h = j >> 9, c = j & 511;
    for (int dp = 0; dp < 64; dp++) acc += wf[WO_W2 + c * 512 + h * 64 + dp] * wf[WO_AE2 + h * 64 + dp];
    cb[CB_WE2 + j] = acc;
  }
}

// --------------------------- flash alignment (MFMA) -------------------------
__global__ __launch_bounds__(256) void flash_mfma_k(const void* __restrict__ Qp, const void* __restrict__ Kp,
                                                    const int* __restrict__ flagp, float* __restrict__ pacc,
                                                    float* __restrict__ pm, float* __restrict__ pz){
  const int fl = *flagp;
  __shared__ __align__(16) u16 Qs[64][72];
  __shared__ __align__(16) u16 Ks[64][72];
  __shared__ __align__(16) u16 Kt[64][72];
  __shared__ __align__(16) u16 Ps[64][72];
  const int t = threadIdx.x;
  const int w = t >> 6;
  const int lane = t & 63;
  const int col = lane & 15;
  const int quad = lane >> 4;
  const int q0 = blockIdx.x * 64;
  const int kbeg = blockIdx.y * 2048;
  {
    const int r = t >> 2, c0 = (t & 3) * 16;
    if (fl){
      const u16* qp = (const u16*)Qp + (size_t)(q0 + r) * 64 + c0;
      for (int c = 0; c < 16; c++) Qs[r][c0 + c] = qp[c];
    } else {
      const float* qp = (const float*)Qp + (size_t)(q0 + r) * 64 + c0;
      for (int c = 0; c < 16; c++) Qs[r][c0 + c] = f2bf(qp[c]);
    }
  }
  f32x4 accO[4];
  #pragma unroll
  for (int d = 0; d < 4; d++) accO[d] = (f32x4){0.f, 0.f, 0.f, 0.f};
  float m_[4], l_[4];
  #pragma unroll
  for (int i = 0; i < 4; i++){ m_[i] = -1e30f; l_[i] = 0.f; }

  for (int kt = 0; kt < 2048; kt += 64){
    __syncthreads();
    {
      const int r = t >> 2, c0 = (t & 3) * 16;
      if (fl){
        const u16* kp = (const u16*)Kp + (size_t)(kbeg + kt + r) * 64 + c0;
        for (int c = 0; c < 16; c++){ u16 v = kp[c]; Ks[r][c0+c] = v; Kt[c0+c][r] = v; }
      } else {
        const float* kp = (const float*)Kp + (size_t)(kbeg + kt + r) * 64 + c0;
        for (int c = 0; c < 16; c++){ u16 v = f2bf(kp[c]); Ks[r][c0+c] = v; Kt[c0+c][r] = v; }
      }
    }
    __syncthreads();
    f32x4 accS[4];
    #pragma unroll
    for (int nt = 0; nt < 4; nt++) accS[nt] = (f32x4){0.f, 0.f, 0.f, 0.f};
    #pragma unroll
    for (int ks = 0; ks < 2; ks++){
      bf16x8 a = *(const bf16x8*)&Qs[w*16 + col][ks*32 + quad*8];
      #pragma unroll
      for (int nt = 0; nt < 4; nt++){
        bf16x8 b = *(const bf16x8*)&Ks[nt*16 + col][ks*32 + quad*8];
        accS[nt] = __builtin_amdgcn_mfma_f32_16x16x32_bf16(a, b, accS[nt], 0, 0, 0);
      }
    }
    #pragma unroll
    for (int i = 0; i < 4; i++){
      float rm = fmaxf(fmaxf(accS[0][i], accS[1][i]), fmaxf(accS[2][i], accS[3][i]));
      rm = fmaxf(rm, __shfl_xor(rm, 1)); rm = fmaxf(rm, __shfl_xor(rm, 2));
      rm = fmaxf(rm, __shfl_xor(rm, 4)); rm = fmaxf(rm, __shfl_xor(rm, 8));
      const float mn = fmaxf(m_[i], rm);
      const float sc = __expf(m_[i] - mn);
      float p0 = __expf(accS[0][i] - mn), p1 = __expf(accS[1][i] - mn);
      float p2 = __expf(accS[2][i] - mn), p3 = __expf(accS[3][i] - mn);
      float rs = p0 + p1 + p2 + p3;
      rs += __shfl_xor(rs, 1); rs += __shfl_xor(rs, 2); rs += __shfl_xor(rs, 4); rs += __shfl_xor(rs, 8);
      l_[i] = l_[i] * sc + rs; m_[i] = mn;
      #pragma unroll
      for (int d = 0; d < 4; d++) accO[d][i] *= sc;
      Ps[w*16 + quad*4 + i][ 0 + col] = f2bf(p0);
      Ps[w*16 + quad*4 + i][16 + col] = f2bf(p1);
      Ps[w*16 + quad*4 + i][32 + col] = f2bf(p2);
      Ps[w*16 + quad*4 + i][48 + col] = f2bf(p3);
    }
    __syncthreads();
    #pragma unroll
    for (int ks = 0; ks < 2; ks++){
      bf16x8 a = *(const bf16x8*)&Ps[w*16 + col][ks*32 + quad*8];
      #pragma unroll
      for (int d = 0; d < 4; d++){
        bf16x8 b = *(const bf16x8*)&Kt[d*16 + col][ks*32 + quad*8];
        accO[d] = __builtin_amdgcn_mfma_f32_16x16x32_bf16(a, b, accO[d], 0, 0, 0);
      }
    }
  }
  #pragma unroll
  for (int i = 0; i < 4; i++){
    const int row = q0 + w*16 + quad*4 + i;
    #pragma unroll
    for (int d = 0; d < 4; d++)
      pacc[((size_t)blockIdx.y * NSd + row) * 64 + d*16 + col] = accO[d][i];
    if (col == 0){ pm[blockIdx.y * NSd + row] = m_[i]; pz[blockIdx.y * NSd + row] = l_[i]; }
  }
}

__global__ __launch_bounds__(256) void flash_merge_k(const float* __restrict__ pacc, const float* __restrict__ pm,
                                                     const float* __restrict__ pz, float* __restrict__ outp){
  const int t = threadIdx.x;
  const int r = blockIdx.x * 4 + (t >> 6);
  const int d = t & 63;
  float M = -1e30f;
  #pragma unroll
  for (int s = 0; s < 4; s++) M = fmaxf(M, pm[s * NSd + r]);
  float Zt = 0.f, v = 0.f;
  #pragma unroll
  for (int s = 0; s < 4; s++){
    const float w = __expf(pm[s * NSd + r] - M);
    Zt += pz[s * NSd + r] * w;
    v  += pacc[((size_t)s * NSd + r) * 64 + d] * w;
  }
  outp[(size_t)r * 64 + d] = v / Zt;
}

// ------------------------------- projection ---------------------------------
__global__ __launch_bounds__(256) void proj_k(const void* __restrict__ nbd1, const void* __restrict__ nbd2,
                                              const float* __restrict__ x1a, const float* __restrict__ x2a,
                                              const float* __restrict__ wf, float* __restrict__ hn0,
                                              const int* __restrict__ flagp){
  const int fl = *flagp;
  __shared__ float At[64][65], Bt[64][65];
  const int t = threadIdx.x, tx = t & 15, ty = t >> 4;
  const int m0 = blockIdx.x * 64;
  float acc[4][4] = {{0.f}};
  for (int kt = 0; kt < 256; kt += 64){
    __syncthreads();
    {
      const int i = t >> 2, c0 = (t & 3) * 16;
      const int mrow = m0 + i;
      const int side = mrow < NSd;
      const int mr = side ? mrow : mrow - NSd;
      const void* nb = side ? nbd1 : nbd2;
      const float* xa = side ? x1a : x2a;
      const int seg = kt >> 6;
      for (int c = 0; c < 16; c++){
        const int kk = c0 + c;
        const float nv = ldin(nb, (size_t)mr * 64 + kk, fl);
        const float av = xa[(size_t)mr * 64 + kk];
        At[i][kk] = (seg == 0) ? nv : (seg == 1) ? av : (seg == 2) ? (nv - av) : (nv * av);
      }
      const int kk = t >> 2;
      for (int c = 0; c < 16; c++) Bt[kk][c0 + c] = wf[WO_PROJ + (kt + kk) * 64 + c0 + c];
    }
    __syncthreads();
    #pragma unroll
    for (int k = 0; k < 64; k++){
      float a0 = At[ty*4+0][k], a1 = At[ty*4+1][k], a2 = At[ty*4+2][k], a3 = At[ty*4+3][k];
      float b0 = Bt[k][tx*4+0], b1 = Bt[k][tx*4+1], b2 = Bt[k][tx*4+2], b3 = Bt[k][tx*4+3];
      acc[0][0] = fmaf(a0,b0,acc[0][0]); acc[0][1] = fmaf(a0,b1,acc[0][1]); acc[0][2] = fmaf(a0,b2,acc[0][2]); acc[0][3] = fmaf(a0,b3,acc[0][3]);
      acc[1][0] = fmaf(a1,b0,acc[1][0]); acc[1][1] = fmaf(a1,b1,acc[1][1]); acc[1][2] = fmaf(a1,b2,acc[1][2]); acc[1][3] = fmaf(a1,b3,acc[1][3]);
      acc[2][0] = fmaf(a2,b0,acc[2][0]); acc[2][1] = fmaf(a2,b1,acc[2][1]); acc[2][2] = fmaf(a2,b2,acc[2][2]); acc[2][3] = fmaf(a2,b3,acc[2][3]);
      acc[3][0] = fmaf(a3,b0,acc[3][0]); acc[3][1] = fmaf(a3,b1,acc[3][1]); acc[3][2] = fmaf(a3,b2,acc[3][2]); acc[3][3] = fmaf(a3,b3,acc[3][3]);
    }
  }
  #pragma unroll
  for (int i = 0; i < 4; i++)
    #pragma unroll
    for (int j = 0; j < 4; j++)
      hn0[(size_t)(m0 + ty*4 + i) * 64 + tx*4 + j] = fmaxf(acc[i][j], 0.f);
}

// ---------------------- per-node combos (block per node) --------------------
template<int K>
__global__ __launch_bounds__(256) void an_node_k(const float* __restrict__ in, const float* __restrict__ wc,
                                                 float* __restrict__ an){
  __shared__ float row[K];
  const int n = blockIdx.x;
  const int t = threadIdx.x;
  for (int c = t; c < K; c += 256) row[c] = in[(size_t)n * K + c];
  __syncthreads();
  const int o = t >> 4, sub = t & 15;
  constexpr int CH = K / 16;
  float acc = 0.f;
  for (int c = 0; c < CH; c++)
    acc = fmaf(row[sub + 16*c], wc[o*K + sub + 16*c], acc);
  acc += __shfl_xor(acc, 1); acc += __shfl_xor(acc, 2);
  acc += __shfl_xor(acc, 4); acc += __shfl_xor(acc, 8);
  if (sub == 0) an[n * 16 + o] = acc;
}

// ------------------------------ small kernels -------------------------------
__global__ __launch_bounds__(256) void u_k(const void* __restrict__ ebd, const float* __restrict__ hn0,
                                           const int* __restrict__ src, float* __restrict__ U,
                                           const int* __restrict__ flagp){
  const int fl = *flagp;
  const int id = blockIdx.x * 256 + threadIdx.x;
  const int e = id >> 6, d = id & 63;
  U[id] = ldin(ebd, id, fl) + hn0[(size_t)src[e] * 64 + d];
}

__global__ __launch_bounds__(256) void s1_k(const void* __restrict__ ebd, const float* __restrict__ cb,
                                            const int* __restrict__ src, const int* __restrict__ dst,
                                            const float* __restrict__ an, float* __restrict__ S,
                                            const int* __restrict__ flagp){
  const int fl = *flagp;
  const int id = blockIdx.x * 256 + threadIdx.x;
  const int e = id >> 3, h = id & 7;
  float a3 = 0.f;
  const float* w = cb + CB_WE1 + h * 64;
  for (int d = 0; d < 64; d++) a3 = fmaf(ldin(ebd, (size_t)e * 64 + d, fl), w[d], a3);
  const float a = an[src[e] * 16 + h] + a3 + an[dst[e] * 16 + 8 + h];
  S[id] = leaky(a);
}

// layer-1 segment softmax -> alpha (edge-id indexed)
__global__ __launch_bounds__(256) void segalpha_k(const float* __restrict__ S, const int* __restrict__ rp,
                                                  const int* __restrict__ cidx, float* __restrict__ AL){
  const int w = blockIdx.x * 4 + (threadIdx.x >> 6);
  const int lane = threadIdx.x & 63;
  const int n = w >> 3, h = w & 7;
  const int beg = rp[n], end = rp[n + 1];
  float m = -1e30f, z = 0.f;
  for (int base = beg; base < end; base += 64){
    const int idx = base + lane;
    float v = -1e30f, cc = 0.f;
    if (idx < end){ v = S[(size_t)cidx[idx] * 8 + h]; cc = 1.f; }
    lse_merge(m, z, v, cc);
  }
  #pragma unroll
  for (int off = 32; off; off >>= 1){
    float om = __shfl_xor(m, off), oz = __shfl_xor(z, off);
    lse_merge(m, z, om, oz);
  }
  const float rz = 1.f / fmaxf(z, 1e-9f);
  for (int base = beg; base < end; base += 64){
    const int idx = base + lane;
    if (idx < end){
      const int e = cidx[idx];
      AL[(size_t)e * 8 + h] = __expf(S[(size_t)e * 8 + h] - m) * rz;
    }
  }
}

// g1[n,h,d] — block per node
__global__ __launch_bounds__(256) void g1b_k(const float* __restrict__ AL, const float* __restrict__ U,
                                             const int* __restrict__ rp, const int* __restrict__ cidx,
                                             float* __restrict__ G1){
  const int n = blockIdx.x;
  const int t = threadIdx.x;
  const int d = t & 63, hh = t >> 6;
  const int beg = rp[n], end = rp[n + 1];
  float a0 = 0.f, a1 = 0.f;
  for (int idx = beg; idx < end; idx++){
    const int e = cidx[idx];
    const float uv = U[(size_t)e * 64 + d];
    a0 = fmaf(AL[(size_t)e * 8 + hh],     uv, a0);
    a1 = fmaf(AL[(size_t)e * 8 + hh + 4], uv, a1);
  }
  G1[(size_t)(n * 8 + hh)     * 64 + d] = a0;
  G1[(size_t)(n * 8 + hh + 4) * 64 + d] = a1;
}

// nft1 tiled GEMM: HNA[n, h*64+c] = elu( sum_k G1[n,h,k] * W1[k, h*64+c] )
__global__ __launch_bounds__(256) void nft1_tile_k(const float* __restrict__ G1, const float* __restrict__ wf,
                                                   float* __restrict__ HNA){
  __shared__ float At[64][65], Bt[64][65];
  const int t = threadIdx.x, tx = t & 15, ty = t >> 4;
  const int h = blockIdx.y;
  const int n0 = blockIdx.x * 64;
  {
    const int i = t >> 2, c0 = (t & 3) * 16;
    const float* gp = G1 + ((size_t)(n0 + i) * 8 + h) * 64 + c0;
    for (int c = 0; c < 16; c++) At[i][c0 + c] = gp[c];
    const int kk = t >> 2;
    const float* wp = wf + WO_W1 + (size_t)kk * 512 + h * 64 + c0;
    for (int c = 0; c < 16; c++) Bt[kk][c0 + c] = wp[c];
  }
  __syncthreads();
  float acc[4][4] = {{0.f}};
  #pragma unroll
  for (int k = 0; k < 64; k++){
    float a0 = At[ty*4+0][k], a1 = At[ty*4+1][k], a2 = At[ty*4+2][k], a3 = At[ty*4+3][k];
    float b0 = Bt[k][tx*4+0], b1 = Bt[k][tx*4+1], b2 = Bt[k][tx*4+2], b3 = Bt[k][tx*4+3];
    acc[0][0] = fmaf(a0,b0,acc[0][0]); acc[0][1] = fmaf(a0,b1,acc[0][1]); acc[0][2] = fmaf(a0,b2,acc[0][2]); acc[0][3] = fmaf(a0,b3,acc[0][3]);
    acc[1][0] = fmaf(a1,b0,acc[1][0]); acc[1][1] = fmaf(a1,b1,acc[1][1]); acc[1][2] = fmaf(a1,b2,acc[1][2]); acc[1][3] = fmaf(a1,b3,acc[1][3]);
    acc[2][0] = fmaf(a2,b0,acc[2][0]); acc[2][1] = fmaf(a2,b1,acc[2][1]); acc[2][2] = fmaf(a2,b2,acc[2][2]); acc[2][3] = fmaf(a2,b3,acc[2][3]);
    acc[3][0] = fmaf(a3,b0,acc[3][0]); acc[3][1] = fmaf(a3,b1,acc[3][1]); acc[3][2] = fmaf(a3,b2,acc[3][2]); acc[3][3] = fmaf(a3,b3,acc[3][3]);
  }
  #pragma unroll
  for (int i = 0; i < 4; i++)
    #pragma unroll
    for (int j = 0; j < 4; j++)
      HNA[(size_t)(n0 + ty*4 + i) * 512 + h * 64 + tx*4 + j] = eluf(acc[i][j]);
}

// slice y: y[ep,c] = elu(alpha1·(U@W1)) + hnA[src], bf16
__global__ __launch_bounds__(256) void y_k(const float* __restrict__ U, const float* __restrict__ AL1,
                                           const float* __restrict__ HNA, const float* __restrict__ wf,
                                           const int* __restrict__ src, const int* __restrict__ cidx,
                                           u16* __restrict__ Y, const int s){
  __shared__ float Us[64][68], Ws[64][68];
  __shared__ int Es[64], Ss[64];
  const int t = threadIdx.x, tx = t & 15, ty = t >> 4;
  const int ep0 = s * 16384 + blockIdx.x * 64;
  if (t < 64){ const int e = cidx[ep0 + t]; Es[t] = e; Ss[t] = src[e]; }
  __syncthreads();
  {
    const int i = t >> 2, c0 = (t & 3) * 16;
    const float* up = U + (size_t)Es[i] * 64 + c0;
    for (int c = 0; c < 16; c++) Us[i][c0 + c] = up[c];
  }
  for (int h = 0; h < 8; h++){
    __syncthreads();
    {
      const int d = t >> 2, c0 = (t & 3) * 16;
      const float* wp = wf + WO_W1 + d * 512 + h * 64 + c0;
      for (int c = 0; c < 16; c++) Ws[d][c0 + c] = wp[c];
    }
    __syncthreads();
    float sv[4][4] = {{0.f}};
    #pragma unroll
    for (int k = 0; k < 64; k++){
      float a0 = Us[ty*4+0][k], a1 = Us[ty*4+1][k], a2 = Us[ty*4+2][k], a3 = Us[ty*4+3][k];
      float b0 = Ws[k][tx*4+0], b1 = Ws[k][tx*4+1], b2 = Ws[k][tx*4+2], b3 = Ws[k][tx*4+3];
      sv[0][0] = fmaf(a0,b0,sv[0][0]); sv[0][1] = fmaf(a0,b1,sv[0][1]); sv[0][2] = fmaf(a0,b2,sv[0][2]); sv[0][3] = fmaf(a0,b3,sv[0][3]);
      sv[1][0] = fmaf(a1,b0,sv[1][0]); sv[1][1] = fmaf(a1,b1,sv[1][1]); sv[1][2] = fmaf(a1,b2,sv[1][2]); sv[1][3] = fmaf(a1,b3,sv[1][3]);
      sv[2][0] = fmaf(a2,b0,sv[2][0]); sv[2][1] = fmaf(a2,b1,sv[2][1]); sv[2][2] = fmaf(a2,b2,sv[2][2]); sv[2][3] = fmaf(a2,b3,sv[2][3]);
      sv[3][0] = fmaf(a3,b0,sv[3][0]); sv[3][1] = fmaf(a3,b1,sv[3][1]); sv[3][2] = fmaf(a3,b2,sv[3][2]); sv[3][3] = fmaf(a3,b3,sv[3][3]);
    }
    #pragma unroll
    for (int i = 0; i < 4; i++){
      const int r = ty*4 + i;
      const float al = AL1[(size_t)Es[r] * 8 + h];
      const float* ha = HNA + (size_t)Ss[r] * 512 + h * 64 + tx*4;
      #pragma unroll
      for (int j = 0; j < 4; j++){
        const float v = eluf(al * sv[i][j]) + ha[j];
        Y[(size_t)(blockIdx.x * 64 + r) * 512 + h * 64 + tx*4 + j] = f2bf(v);
      }
    }
  }
}

// layer-2 scores from Y: S2[pos,h2] = leaky(AN2c[se,h2] + <Y[pos,:],WE2[h2,:]> + AN2[de,8+h2])
// (AN2 rows 0..8 already have -anE folded in). Wave per edge.
__global__ __launch_bounds__(256) void s2y_k(const u16* __restrict__ Y, const float* __restrict__ cb,
                                             const float* __restrict__ AN2, const int* __restrict__ src,
                                             const int* __restrict__ dst, const int* __restrict__ cidx,
                                             float* __restrict__ SA, const int s){
  __shared__ float Wt[4096];   // transposed WE2: Wt[c*8+h2] -> broadcast LDS reads
  const int t = threadIdx.x;
  for (int idx = t; idx < 4096; idx += 256){
    const int c = idx >> 3, h2 = idx & 7;
    Wt[idx] = cb[CB_WE2 + h2 * 512 + c];
  }
  __syncthreads();
  const int w = t >> 6, lane = t & 63;
  const int pos = s * 16384 + blockIdx.x * 4 + w;
  const int epl = pos - s * 16384;
  const ushort4 y0 = *(const ushort4*)(Y + (size_t)epl * 512 + lane * 8);
  const ushort4 y1 = *(const ushort4*)(Y + (size_t)epl * 512 + lane * 8 + 4);
  float yv[8] = { bf2f(y0.x), bf2f(y0.y), bf2f(y0.z), bf2f(y0.w),
                  bf2f(y1.x), bf2f(y1.y), bf2f(y1.z), bf2f(y1.w) };
  float acc[8] = {0.f};
  #pragma unroll
  for (int j = 0; j < 8; j++){
    const float* wp = Wt + (lane * 8 + j) * 8;
    #pragma unroll
    for (int h2 = 0; h2 < 8; h2++) acc[h2] = fmaf(yv[j], wp[h2], acc[h2]);
  }
  #pragma unroll
  for (int h2 = 0; h2 < 8; h2++){
    float v = acc[h2];
    v += __shfl_xor(v, 1); v += __shfl_xor(v, 2); v += __shfl_xor(v, 4);
    v += __shfl_xor(v, 8); v += __shfl_xor(v, 16); v += __shfl_xor(v, 32);
    acc[h2] = v;
  }
  if (lane == 0){
    const int e = cidx[pos];
    const int se = src[e], de = dst[e];
    #pragma unroll
    for (int h2 = 0; h2 < 8; h2++)
      SA[(size_t)pos * 8 + h2] = leaky(AN2[se * 16 + h2] + acc[h2] + AN2[de * 16 + 8 + h2]);
  }
}

// layer-2 segment softmax, position-indexed, in-place S -> alpha
__global__ __launch_bounds__(256) void segalpha2_k(float* __restrict__ SA, const int* __restrict__ rp,
                                                   const int s){
  const int w = blockIdx.x * 4 + (threadIdx.x >> 6);
  const int lane = threadIdx.x & 63;
  const int n = s * 2048 + (w >> 3), h = w & 7;
  const int beg = rp[n], end = rp[n + 1];
  float m = -1e30f, z = 0.f;
  for (int base = beg; base < end; base += 64){
    const int idx = base + lane;
    float v = -1e30f, cc = 0.f;
    if (idx < end){ v = SA[(size_t)idx * 8 + h]; cc = 1.f; }
    lse_merge(m, z, v, cc);
  }
  #pragma unroll
  for (int off = 32; off; off >>= 1){
    float om = __shfl_xor(m, off), oz = __shfl_xor(z, off);
    lse_merge(m, z, om, oz);
  }
  const float rz = 1.f / fmaxf(z, 1e-9f);
  for (int base = beg; base < end; base += 64){
    const int idx = base + lane;
    if (idx < end)
      SA[(size_t)idx * 8 + h] = __expf(SA[(size_t)idx * 8 + h] - m) * rz;
  }
}

// slice g2 (bf16): g2[nl,h,c] = sum_pos alpha2[pos,h]*y[epl,c]  (alpha contiguous)
__global__ __launch_bounds__(256) void g2_k(const float* __restrict__ SA, const u16* __restrict__ Y,
                                            const int* __restrict__ rp, u16* __restrict__ G2, const int s){
  const int t = threadIdx.x;
  const int nl = blockIdx.x;
  const int n = s * 2048 + nl;
  const int d4 = (t & 127) * 4;
  const int hh = (t >> 7) * 4;
  const int beg = rp[n], end = rp[n + 1];
  const int base = s * 16384;
  float acc[4][4] = {{0.f}};
  for (int pos = beg; pos < end; pos++){
    const int epl = pos - base;
    const float4 a4 = *(const float4*)(SA + (size_t)pos * 8 + hh);
    const ushort4 yv = *(const ushort4*)(Y + (size_t)epl * 512 + d4);
    const float y0 = bf2f(yv.x), y1 = bf2f(yv.y), y2 = bf2f(yv.z), y3 = bf2f(yv.w);
    acc[0][0] = fmaf(a4.x, y0, acc[0][0]); acc[0][1] = fmaf(a4.x, y1, acc[0][1]); acc[0][2] = fmaf(a4.x, y2, acc[0][2]); acc[0][3] = fmaf(a4.x, y3, acc[0][3]);
    acc[1][0] = fmaf(a4.y, y0, acc[1][0]); acc[1][1] = fmaf(a4.y, y1, acc[1][1]); acc[1][2] = fmaf(a4.y, y2, acc[1][2]); acc[1][3] = fmaf(a4.y, y3, acc[1][3]);
    acc[2][0] = fmaf(a4.z, y0, acc[2][0]); acc[2][1] = fmaf(a4.z, y1, acc[2][1]); acc[2][2] = fmaf(a4.z, y2, acc[2][2]); acc[2][3] = fmaf(a4.z, y3, acc[2][3]);
    acc[3][0] = fmaf(a4.w, y0, acc[3][0]); acc[3][1] = fmaf(a4.w, y1, acc[3][1]); acc[3][2] = fmaf(a4.w, y2, acc[3][2]); acc[3][3] = fmaf(a4.w, y3, acc[3][3]);
  }
  #pragma unroll
  for (int hi = 0; hi < 4; hi++)
    #pragma unroll
    for (int di = 0; di < 4; di++)
      G2[((size_t)nl * 8 + hh + hi) * 512 + d4 + di] = f2bf(acc[hi][di]);
}

// slice nft2: hnB16[n, h*64+c] = elu( sum_k g2[nl,h,k] * W2[k, h*64+c] )  (bf16 out)
__global__ __launch_bounds__(256) void nft2_k(const u16* __restrict__ G2, const float* __restrict__ wf,
                                              u16* __restrict__ HNB, const int s){
  __shared__ float At[64][65], Bt[64][65];
  const int t = threadIdx.x, tx = t & 15, ty = t >> 4;
  const int h = blockIdx.y;
  const int nl0 = blockIdx.x * 64;
  float acc[4][4] = {{0.f}};
  for (int kt = 0; kt < 512; kt += 64){
    __syncthreads();
    {
      const int i = t >> 2, c0 = (t & 3) * 16;
      const u16* gp = G2 + ((size_t)(nl0 + i) * 8 + h) * 512 + kt + c0;
      for (int c = 0; c < 16; c++) At[i][c0 + c] = bf2f(gp[c]);
      const int kk = t >> 2;
      const float* wp = wf + WO_W2 + (size_t)(kt + kk) * 512 + h * 64 + c0;
      for (int c = 0; c < 16; c++) Bt[kk][c0 + c] = wp[c];
    }
    __syncthreads();
    #pragma unroll
    for (int k = 0; k < 64; k++){
      float a0 = At[ty*4+0][k], a1 = At[ty*4+1][k], a2 = At[ty*4+2][k], a3 = At[ty*4+3][k];
      float b0 = Bt[k][tx*4+0], b1 = Bt[k][tx*4+1], b2 = Bt[k][tx*4+2], b3 = Bt[k][tx*4+3];
      acc[0][0] = fmaf(a0,b0,acc[0][0]); acc[0][1] = fmaf(a0,b1,acc[0][1]); acc[0][2] = fmaf(a0,b2,acc[0][2]); acc[0][3] = fmaf(a0,b3,acc[0][3]);
      acc[1][0] = fmaf(a1,b0,acc[1][0]); acc[1][1] = fmaf(a1,b1,acc[1][1]); acc[1][2] = fmaf(a1,b2,acc[1][2]); acc[1][3] = fmaf(a1,b3,acc[1][3]);
      acc[2][0] = fmaf(a2,b0,acc[2][0]); acc[2][1] = fmaf(a2,b1,acc[2][1]); acc[2][2] = fmaf(a2,b2,acc[2][2]); acc[2][3] = fmaf(a2,b3,acc[2][3]);
      acc[3][0] = fmaf(a3,b0,acc[3][0]); acc[3][1] = fmaf(a3,b1,acc[3][1]); acc[3][2] = fmaf(a3,b2,acc[3][2]); acc[3][3] = fmaf(a3,b3,acc[3][3]);
    }
  }
  #pragma unroll
  for (int i = 0; i < 4; i++)
    #pragma unroll
    for (int j = 0; j < 4; j++)
      HNB[(size_t)(s * 2048 + nl0 + ty*4 + i) * 512 + h * 64 + tx*4 + j] = f2bf(eluf(acc[i][j]));
}

// ---------------------------------- CSR -------------------------------------
__global__ __launch_bounds__(256) void hist_k(const int* __restrict__ dst, int* __restrict__ deg){
  const int e = blockIdx.x * 256 + threadIdx.x;
  if (e < NEd) atomicAdd(&deg[dst[e]], 1);
}
__global__ __launch_bounds__(256) void scan_k(const int* __restrict__ deg, int* __restrict__ rp,
                                              int* __restrict__ fill){
  __shared__ int ps[257];
  const int t = threadIdx.x;
  const int base = t * 64;
  int s = 0;
  for (int i = 0; i < 64; i++) s += deg[base + i];
  ps[t + 1] = s;
  if (t == 0) ps[0] = 0;
  __syncthreads();
  if (t == 0) for (int i = 1; i <= 256; i++) ps[i] += ps[i - 1];
  __syncthreads();
  int off = ps[t];
  for (int i = 0; i < 64; i++){ rp[base + i] = off; fill[base + i] = off; off += deg[base + i]; }
  if (t == 255) rp[NNd] = off;
}
__global__ __launch_bounds__(256) void scatter_k(const int* __restrict__ dst, int* __restrict__ fill,
                                                 int* __restrict__ cidx){
  const int e = blockIdx.x * 256 + threadIdx.x;
  if (e < NEd){ int pos = atomicAdd(&fill[dst[e]], 1); cidx[pos] = e; }
}

// ------------------------------- readout ------------------------------------
__global__ __launch_bounds__(256) void mean_k(const u16* __restrict__ HNB, float* __restrict__ xcat){
  const int sg = blockIdx.x;   // 0..31
  const int t = threadIdx.x;
  const int g = (sg < 16) ? sg : sg - 16;
  const int half = (sg < 16) ? 0 : 1;
  for (int c = t; c < 512; c += 256){
    float s = 0.f;
    const u16* base = HNB + (size_t)sg * 512 * 512 + c;
    for (int n = 0; n < 512; n++) s += bf2f(base[(size_t)n * 512]);
    xcat[g * 1024 + half * 512 + c] = s * (1.f / 512.f);
  }
}

__global__ __launch_bounds__(1024) void head_k(float* __restrict__ xcat, const float* __restrict__ wf,
                                               void* __restrict__ outp, const int* __restrict__ flagp){
  __shared__ float y1[16][64];
  __shared__ float y2[16][64];
  __shared__ float mu2s[64], sc2s[64];
  const int t = threadIdx.x;
  {
    float mu = 0.f;
    #pragma unroll
    for (int g = 0; g < 16; g++) mu += xcat[g * 1024 + t];
    mu *= (1.f / 16.f);
    float var = 0.f;
    #pragma unroll
    for (int g = 0; g < 16; g++){ float d = xcat[g * 1024 + t] - mu; var += d * d; }
    var *= (1.f / 16.f);
    const float sc = rsqrtf(var + 1e-5f) * wf[WO_B1G + t];
    const float sh = wf[WO_B1B + t] - mu * sc;
    #pragma unroll
    for (int g = 0; g < 16; g++) xcat[g * 1024 + t] = xcat[g * 1024 + t] * sc + sh;
  }
  __syncthreads();
  {
    const int gg = t >> 6, c = t & 63;
    float acc = wf[WO_F1B + c];
    for (int k = 0; k < 1024; k++) acc = fmaf(xcat[gg * 1024 + k], wf[WO_F1W + k * 64 + c], acc);
    y1[gg][c] = fmaxf(acc, 0.f);
  }
  __syncthreads();
  if (t < 64){
    float mu = 0.f;
    #pragma unroll
    for (int g = 0; g < 16; g++) mu += y1[g][t];
    mu *= (1.f / 16.f);
    float var = 0.f;
    #pragma unroll
    for (int g = 0; g < 16; g++){ float d = y1[g][t] - mu; var += d * d; }
    var *= (1.f / 16.f);
    mu2s[t] = mu; sc2s[t] = rsqrtf(var + 1e-5f) * wf[WO_B2G + t];
  }
  __syncthreads();
  {
    const int gg = t >> 6, c = t & 63;
    y2[gg][c] = (y1[gg][c] - mu2s[c]) * sc2s[c] + wf[WO_B2B + c];
  }
  __syncthreads();
  if (t < 48){
    const int gg = t / 3, c = t % 3;
    float acc = wf[WO_F2B + c];
    #pragma unroll
    for (int k = 0; k < 64; k++) acc = fmaf(y2[gg][k], wf[WO_F2W + k * 3 + c], acc);
    if (*flagp) ((u16*)outp)[t] = f2bf(acc);
    else        ((float*)outp)[t] = acc;
  }
}

// --------------------------------- launch -----------------------------------
extern "C" void kernel_launch(void* const* d_in, const int* in_sizes, int n_in,
                              void* d_out, int out_size, void* d_ws, size_t ws_size,
                              hipStream_t stream) {
  (void)in_sizes; (void)n_in; (void)out_size;
  if (ws_size < WS_NEED) return;

  const int* src = (const int*)d_in[3];
  const int* dst = (const int*)d_in[4];
  char* w = (char*)d_ws;

  float* wf   = (float*)(w + OFF_WF);
  float* cb   = (float*)(w + OFF_CB);
  float* U    = (float*)(w + OFF_U);
  float* AL1  = (float*)(w + OFF_AL1);
  float* SA   = (float*)(w + OFF_SA);
  float* HNA  = (float*)(w + OFF_HNA);
  int*   deg  = (int*)(w + OFF_DEG);
  int*   rp   = (int*)(w + OFF_RP);
  int*   fill = (int*)(w + OFF_FILL);
  int*   cidx = (int*)(w + OFF_CIDX);
  float* rbig = (float*)(w + OFF_RBIG);
  float* xcat = (float*)(w + OFF_XCAT);
  int*   flag = (int*)(w + OFF_FLAG);

  float* x1a  = (float*)(w + OFF_T + T_X1A);
  float* x2a  = (float*)(w + OFF_T + T_X2A);
  float* hn0  = (float*)(w + OFF_T + T_HN0);
  float* AN1  = (float*)(w + OFF_T + T_AN1);
  float* S    = (float*)(w + OFF_T + T_S);
  u16*   Y    = (u16*)(w + OFF_T + T_Y);
  u16*   G2   = (u16*)(w + OFF_T + T_G2);

  float* pacc = rbig;
  float* pm   = (float*)(w + OFF_RBIG + R_PM);
  float* pz   = (float*)(w + OFF_RBIG + R_PZ);
  float* G1   = rbig;                              // layer-1 phase
  u16*   HNB  = (u16*)(w + OFF_RBIG);              // slice phase (bf16, 16.7MB)
  float* AN2  = (float*)(w + OFF_RBIG + R_AN2);    // above HNB16

  // 0. detect + weights + combos
  detect_k<<<1, 256, 0, stream>>>((const u16*)d_in[0], flag);
  P17 ps;
  for (int i = 0; i < 17; i++) ps.p[i] = d_in[6 + i];
  convw_k<<<(WO_END + 255) / 256, 256, 0, stream>>>(ps, wf, flag);
  combos_k<<<(CB_END + 255) / 256, 256, 0, stream>>>(wf, cb);

  // 1. CSR over dst
  hipMemsetAsync(deg, 0, NNd * sizeof(int), stream);
  hist_k<<<NEd / 256, 256, 0, stream>>>(dst, deg);
  scan_k<<<1, 256, 0, stream>>>(deg, rp, fill);
  scatter_k<<<NEd / 256, 256, 0, stream>>>(dst, fill, cidx);

  // 2. alignment (MFMA flash)
  flash_mfma_k<<<dim3(128, 4), 256, 0, stream>>>(d_in[0], d_in[1], flag, pacc, pm, pz);
  flash_merge_k<<<NSd / 4, 256, 0, stream>>>(pacc, pm, pz, x1a);
  flash_mfma_k<<<dim3(128, 4), 256, 0, stream>>>(d_in[1], d_in[0], flag, pacc, pm, pz);
  flash_merge_k<<<NSd / 4, 256, 0, stream>>>(pacc, pm, pz, x2a);

  // 3. projection
  proj_k<<<NNd / 64, 256, 0, stream>>>(d_in[0], d_in[1], x1a, x2a, wf, hn0, flag);

  // 4. GAT layer 1
  an_node_k<64><<<NNd, 256, 0, stream>>>(hn0, cb + CB_WC1, AN1);
  u_k<<<NEd * 64 / 256, 256, 0, stream>>>(d_in[2], hn0, src, U, flag);
  s1_k<<<NEd * 8 / 256, 256, 0, stream>>>(d_in[2], cb, src, dst, AN1, S, flag);
  segalpha_k<<<NNd * 8 / 4, 256, 0, stream>>>(S, rp, cidx, AL1);
  g1b_k<<<NNd, 256, 0, stream>>>(AL1, U, rp, cidx, G1);
  nft1_tile_k<<<dim3(NNd / 64, 8), 256, 0, stream>>>(G1, wf, HNA);

  // 5. layer-2 per-node combos (a1-anE folded, a2)
  an_node_k<512><<<NNd, 256, 0, stream>>>(HNA, cb + CB_WC2, AN2);

  // 6. layer-2: 8 slices, fully slice-local (scores from Y, in-place softmax)
  for (int s = 0; s < 8; s++){
    y_k<<<256, 256, 0, stream>>>(U, AL1, HNA, wf, src, cidx, Y, s);
    s2y_k<<<4096, 256, 0, stream>>>(Y, cb, AN2, src, dst, cidx, SA, s);
    segalpha2_k<<<4096, 256, 0, stream>>>(SA, rp, s);
    g2_k<<<2048, 256, 0, stream>>>(SA, Y, rp, G2, s);
    nft2_k<<<dim3(32, 8), 256, 0, stream>>>(G2, wf, HNB, s);
  }

  // 7. readout
  mean_k<<<32, 256, 0, stream>>>(HNB, xcat);
  head_k<<<1, 1024, 0, stream>>>(xcat, wf, d_out, flag);
}

// Round 5
// 1530.620 us; speedup vs baseline: 3.1024x; 1.5331x over previous
//
#include <hip/hip_runtime.h>

// GATClassifier on MI355X — round 5: y_k -> MFMA (y2_k) with fused layer-2
// score dot (s2y eliminated); U stored bf16; W1 preconverted bf16; mean_k
// coalesced. ws layout unchanged (144.98 MB proven safe).

#define NSd 8192
#define NNd 16384
#define NEd 131072

typedef unsigned short u16;
typedef unsigned int   u32;
typedef short bf16x8 __attribute__((ext_vector_type(8)));
typedef float f32x4  __attribute__((ext_vector_type(4)));

__device__ __forceinline__ float bf2f(u16 u){ return __uint_as_float(((u32)u) << 16); }
__device__ __forceinline__ u16 f2bf(float f){
  u32 u = __float_as_uint(f);
  u += 0x7fffu + ((u >> 16) & 1u);
  return (u16)(u >> 16);
}
__device__ __forceinline__ float eluf(float x){ return x > 0.f ? x : expm1f(x); }
__device__ __forceinline__ float leaky(float x){ return x > 0.f ? x : 0.2f * x; }
__device__ __forceinline__ float ldin(const void* p, size_t i, int fl){
  return fl ? bf2f(((const u16*)p)[i]) : ((const float*)p)[i];
}
__device__ __forceinline__ void lse_merge(float& m, float& z, float om, float oz){
  float M = fmaxf(m, om);
  z = z * __expf(m - M) + oz * __expf(om - M);
  m = M;
}

// ------------------------- workspace layout (bytes) -------------------------
static constexpr size_t OFF_WF   = 0;            // 382339 f32 weights
static constexpr size_t OFF_CB   = 1529600;      // 13824 f32 combos
static constexpr size_t OFF_U    = 1584896;      // 131072*64 bf16 (Ub)
static constexpr size_t OFF_W1B  = 18362112;     // 32768 bf16 (W1 preconverted)
static constexpr size_t OFF_AL1  = 35139328;     // 131072*8 f32 (edge-id idx)
static constexpr size_t OFF_SA   = 39333632;     // 131072*8 f32 S2/alpha2 by CSR pos
static constexpr size_t OFF_HNA  = 43527936;     // 16384*512 f32
static constexpr size_t OFF_DEG  = 77082368;     // 16384 int
static constexpr size_t OFF_RP   = 77147904;     // 16385 int (padded)
static constexpr size_t OFF_FILL = 77213696;
static constexpr size_t OFF_CIDX = 77279232;     // 131072 int
static constexpr size_t OFF_RBIG = 77803520;     // 33.5MB: flash | G1 | HNB16+AN2
static constexpr size_t OFF_T    = 111357952;    // 32MB union region
static constexpr size_t OFF_XCAT = 144912384;
static constexpr size_t OFF_FLAG = 144977920;
static constexpr size_t WS_NEED  = 144978176;

// T-union (early phase)
static constexpr size_t T_X1A = 0;               // 8192*64 f32
static constexpr size_t T_X2A = 2097152;
static constexpr size_t T_HN0 = 4194304;         // 16384*64 f32
static constexpr size_t T_AN1 = 8388608;         // 16384*16 f32
static constexpr size_t T_S   = 9437184;         // 131072*8 f32 (layer-1, edge-id)
// T-union (slice phase, NS=8)
static constexpr size_t T_Y   = 0;               // 16384*512 bf16
static constexpr size_t T_G2  = 16777216;        // 2048*8*512 bf16
// RBIG sub-offsets
static constexpr size_t R_PM  = 8388608;
static constexpr size_t R_PZ  = 8519680;
static constexpr size_t R_AN2 = 16777216;        // 16384*16 f32 above HNB16

// weight offsets (floats within OFF_WF)
static constexpr int WO_PROJ = 0,      WO_W1 = 16384;
static constexpr int WO_AL1 = 49152,   WO_AR1 = 49664,  WO_AE1 = 50176;
static constexpr int WO_W2  = 50688;
static constexpr int WO_AL2 = 312832,  WO_AR2 = 313344, WO_AE2 = 313856;
static constexpr int WO_B1G = 314368,  WO_B1B = 315392;
static constexpr int WO_F1W = 316416,  WO_F1B = 381952;
static constexpr int WO_B2G = 382016,  WO_B2B = 382080;
static constexpr int WO_F2W = 382144,  WO_F2B = 382336;
static constexpr int WO_END = 382339;

// combo offsets (floats within OFF_CB)
static constexpr int CB_WC1 = 0;      // [16][64]
static constexpr int CB_WE1 = 1024;   // [8][64]
static constexpr int CB_WC2 = 1536;   // [16][512]  rows 0..7 = W2*(al2-ae2)
static constexpr int CB_WE2 = 9728;   // [8][512]
static constexpr int CB_END = 13824;

// ------------------------------- dtype detect -------------------------------
__global__ __launch_bounds__(256) void detect_k(const u16* __restrict__ p, int* __restrict__ flag){
  __shared__ int bad;
  if (threadIdx.x == 0) bad = 0;
  __syncthreads();
  int b = 0;
  for (int i = threadIdx.x; i < 1024; i += 256){
    float f = bf2f(p[i]);
    if (!(fabsf(f) <= 100.f)) b++;
  }
  atomicAdd(&bad, b);
  __syncthreads();
  if (threadIdx.x == 0) *flag = (bad == 0) ? 1 : 0;
}

struct P17 { const void* p[17]; };

__global__ __launch_bounds__(256) void convw_k(P17 ps, float* __restrict__ wf, const int* __restrict__ flagp){
  const int i = blockIdx.x * 256 + threadIdx.x;
  if (i >= WO_END) return;
  const int fl = *flagp;
  const int ends[17] = {16384,49152,49664,50176,50688,312832,313344,313856,314368,
                        315392,316416,381952,382016,382080,382144,382336,382339};
  int seg = 0;
  while (i >= ends[seg]) seg++;
  const int start = seg ? ends[seg-1] : 0;
  wf[i] = ldin(ps.p[seg], i - start, fl);
}

__global__ __launch_bounds__(256) void convw1b_k(const float* __restrict__ wf, u16* __restrict__ w1b){
  const int i = blockIdx.x * 256 + threadIdx.x;
  if (i < 32768) w1b[i] = f2bf(wf[WO_W1 + i]);
}

__global__ __launch_bounds__(256) void combos_k(const float* __restrict__ wf, float* __restrict__ cb){
  const int i = blockIdx.x * 256 + threadIdx.x;
  if (i >= CB_END) return;
  float acc = 0.f;
  if (i < 1024){
    const int o = i >> 6, d = i & 63, h = o & 7;
    const float* a = wf + ((o >> 3) ? WO_AR1 : WO_AL1) + h * 64;
    for (int dp = 0; dp < 64; dp++) acc += wf[WO_W1 + d * 512 + h * 64 + dp] * a[dp];
    cb[CB_WC1 + i] = acc;
  } else if (i < 1536){
    const int j = i - 1024, h = j >> 6, d = j & 63;
    for (int dp = 0; dp < 64; dp++) acc += wf[WO_W1 + d * 512 + h * 64 + dp] * wf[WO_AE1 + h * 64 + dp];
    cb[CB_WE1 + j] = acc;
  } else if (i < 9728){
    const int j = i - 1536, o = j >> 9, c = j & 511, h = o & 7;
    for (int dp = 0; dp < 64; dp++){
      const float av = (o >> 3) ? wf[WO_AR2 + h * 64 + dp]
                                : (wf[WO_AL2 + h * 64 + dp] - wf[WO_AE2 + h * 64 + dp]);
      acc += wf[WO_W2 + c * 512 + h * 64 + dp] * av;
    }
    cb[CB_WC2 + j] = acc;
  } else {
    const int j = i - 9728, h = j >> 9, c = j & 511;
    for (int dp = 0; dp < 64; dp++) acc += wf[WO_W2 + c * 512 + h * 64 + dp] * wf[WO_AE2 + h * 64 + dp];
    cb[CB_WE2 + j] = acc;
  }
}

// --------------------------- flash alignment (MFMA) -------------------------
__global__ __launch_bounds__(256) void flash_mfma_k(const void* __restrict__ Qp, const void* __restrict__ Kp,
                                                    const int* __restrict__ flagp, float* __restrict__ pacc,
                                                    float* __restrict__ pm, float* __restrict__ pz){
  const int fl = *flagp;
  __shared__ __align__(16) u16 Qs[64][72];
  __shared__ __align__(16) u16 Ks[64][72];
  __shared__ __align__(16) u16 Kt[64][72];
  __shared__ __align__(16) u16 Ps[64][72];
  const int t = threadIdx.x;
  const int w = t >> 6;
  const int lane = t & 63;
  const int col = lane & 15;
  const int quad = lane >> 4;
  const int q0 = blockIdx.x * 64;
  const int kbeg = blockIdx.y * 2048;
  {
    const int r = t >> 2, c0 = (t & 3) * 16;
    if (fl){
      const u16* qp = (const u16*)Qp + (size_t)(q0 + r) * 64 + c0;
      for (int c = 0; c < 16; c++) Qs[r][c0 + c] = qp[c];
    } else {
      const float* qp = (const float*)Qp + (size_t)(q0 + r) * 64 + c0;
      for (int c = 0; c < 16; c++) Qs[r][c0 + c] = f2bf(qp[c]);
    }
  }
  f32x4 accO[4];
  #pragma unroll
  for (int d = 0; d < 4; d++) accO[d] = (f32x4){0.f, 0.f, 0.f, 0.f};
  float m_[4], l_[4];
  #pragma unroll
  for (int i = 0; i < 4; i++){ m_[i] = -1e30f; l_[i] = 0.f; }

  for (int kt = 0; kt < 2048; kt += 64){
    __syncthreads();
    {
      const int r = t >> 2, c0 = (t & 3) * 16;
      if (fl){
        const u16* kp = (const u16*)Kp + (size_t)(kbeg + kt + r) * 64 + c0;
        for (int c = 0; c < 16; c++){ u16 v = kp[c]; Ks[r][c0+c] = v; Kt[c0+c][r] = v; }
      } else {
        const float* kp = (const float*)Kp + (size_t)(kbeg + kt + r) * 64 + c0;
        for (int c = 0; c < 16; c++){ u16 v = f2bf(kp[c]); Ks[r][c0+c] = v; Kt[c0+c][r] = v; }
      }
    }
    __syncthreads();
    f32x4 accS[4];
    #pragma unroll
    for (int nt = 0; nt < 4; nt++) accS[nt] = (f32x4){0.f, 0.f, 0.f, 0.f};
    #pragma unroll
    for (int ks = 0; ks < 2; ks++){
      bf16x8 a = *(const bf16x8*)&Qs[w*16 + col][ks*32 + quad*8];
      #pragma unroll
      for (int nt = 0; nt < 4; nt++){
        bf16x8 b = *(const bf16x8*)&Ks[nt*16 + col][ks*32 + quad*8];
        accS[nt] = __builtin_amdgcn_mfma_f32_16x16x32_bf16(a, b, accS[nt], 0, 0, 0);
      }
    }
    #pragma unroll
    for (int i = 0; i < 4; i++){
      float rm = fmaxf(fmaxf(accS[0][i], accS[1][i]), fmaxf(accS[2][i], accS[3][i]));
      rm = fmaxf(rm, __shfl_xor(rm, 1)); rm = fmaxf(rm, __shfl_xor(rm, 2));
      rm = fmaxf(rm, __shfl_xor(rm, 4)); rm = fmaxf(rm, __shfl_xor(rm, 8));
      const float mn = fmaxf(m_[i], rm);
      const float sc = __expf(m_[i] - mn);
      float p0 = __expf(accS[0][i] - mn), p1 = __expf(accS[1][i] - mn);
      float p2 = __expf(accS[2][i] - mn), p3 = __expf(accS[3][i] - mn);
      float rs = p0 + p1 + p2 + p3;
      rs += __shfl_xor(rs, 1); rs += __shfl_xor(rs, 2); rs += __shfl_xor(rs, 4); rs += __shfl_xor(rs, 8);
      l_[i] = l_[i] * sc + rs; m_[i] = mn;
      #pragma unroll
      for (int d = 0; d < 4; d++) accO[d][i] *= sc;
      Ps[w*16 + quad*4 + i][ 0 + col] = f2bf(p0);
      Ps[w*16 + quad*4 + i][16 + col] = f2bf(p1);
      Ps[w*16 + quad*4 + i][32 + col] = f2bf(p2);
      Ps[w*16 + quad*4 + i][48 + col] = f2bf(p3);
    }
    __syncthreads();
    #pragma unroll
    for (int ks = 0; ks < 2; ks++){
      bf16x8 a = *(const bf16x8*)&Ps[w*16 + col][ks*32 + quad*8];
      #pragma unroll
      for (int d = 0; d < 4; d++){
        bf16x8 b = *(const bf16x8*)&Kt[d*16 + col][ks*32 + quad*8];
        accO[d] = __builtin_amdgcn_mfma_f32_16x16x32_bf16(a, b, accO[d], 0, 0, 0);
      }
    }
  }
  #pragma unroll
  for (int i = 0; i < 4; i++){
    const int row = q0 + w*16 + quad*4 + i;
    #pragma unroll
    for (int d = 0; d < 4; d++)
      pacc[((size_t)blockIdx.y * NSd + row) * 64 + d*16 + col] = accO[d][i];
    if (col == 0){ pm[blockIdx.y * NSd + row] = m_[i]; pz[blockIdx.y * NSd + row] = l_[i]; }
  }
}

__global__ __launch_bounds__(256) void flash_merge_k(const float* __restrict__ pacc, const float* __restrict__ pm,
                                                     const float* __restrict__ pz, float* __restrict__ outp){
  const int t = threadIdx.x;
  const int r = blockIdx.x * 4 + (t >> 6);
  const int d = t & 63;
  float M = -1e30f;
  #pragma unroll
  for (int s = 0; s < 4; s++) M = fmaxf(M, pm[s * NSd + r]);
  float Zt = 0.f, v = 0.f;
  #pragma unroll
  for (int s = 0; s < 4; s++){
    const float w = __expf(pm[s * NSd + r] - M);
    Zt += pz[s * NSd + r] * w;
    v  += pacc[((size_t)s * NSd + r) * 64 + d] * w;
  }
  outp[(size_t)r * 64 + d] = v / Zt;
}

// ------------------------------- projection ---------------------------------
__global__ __launch_bounds__(256) void proj_k(const void* __restrict__ nbd1, const void* __restrict__ nbd2,
                                              const float* __restrict__ x1a, const float* __restrict__ x2a,
                                              const float* __restrict__ wf, float* __restrict__ hn0,
                                              const int* __restrict__ flagp){
  const int fl = *flagp;
  __shared__ float At[64][65], Bt[64][65];
  const int t = threadIdx.x, tx = t & 15, ty = t >> 4;
  const int m0 = blockIdx.x * 64;
  float acc[4][4] = {{0.f}};
  for (int kt = 0; kt < 256; kt += 64){
    __syncthreads();
    {
      const int i = t >> 2, c0 = (t & 3) * 16;
      const int mrow = m0 + i;
      const int side = mrow < NSd;
      const int mr = side ? mrow : mrow - NSd;
      const void* nb = side ? nbd1 : nbd2;
      const float* xa = side ? x1a : x2a;
      const int seg = kt >> 6;
      for (int c = 0; c < 16; c++){
        const int kk = c0 + c;
        const float nv = ldin(nb, (size_t)mr * 64 + kk, fl);
        const float av = xa[(size_t)mr * 64 + kk];
        At[i][kk] = (seg == 0) ? nv : (seg == 1) ? av : (seg == 2) ? (nv - av) : (nv * av);
      }
      const int kk = t >> 2;
      for (int c = 0; c < 16; c++) Bt[kk][c0 + c] = wf[WO_PROJ + (kt + kk) * 64 + c0 + c];
    }
    __syncthreads();
    #pragma unroll
    for (int k = 0; k < 64; k++){
      float a0 = At[ty*4+0][k], a1 = At[ty*4+1][k], a2 = At[ty*4+2][k], a3 = At[ty*4+3][k];
      float b0 = Bt[k][tx*4+0], b1 = Bt[k][tx*4+1], b2 = Bt[k][tx*4+2], b3 = Bt[k][tx*4+3];
      acc[0][0] = fmaf(a0,b0,acc[0][0]); acc[0][1] = fmaf(a0,b1,acc[0][1]); acc[0][2] = fmaf(a0,b2,acc[0][2]); acc[0][3] = fmaf(a0,b3,acc[0][3]);
      acc[1][0] = fmaf(a1,b0,acc[1][0]); acc[1][1] = fmaf(a1,b1,acc[1][1]); acc[1][2] = fmaf(a1,b2,acc[1][2]); acc[1][3] = fmaf(a1,b3,acc[1][3]);
      acc[2][0] = fmaf(a2,b0,acc[2][0]); acc[2][1] = fmaf(a2,b1,acc[2][1]); acc[2][2] = fmaf(a2,b2,acc[2][2]); acc[2][3] = fmaf(a2,b3,acc[2][3]);
      acc[3][0] = fmaf(a3,b0,acc[3][0]); acc[3][1] = fmaf(a3,b1,acc[3][1]); acc[3][2] = fmaf(a3,b2,acc[3][2]); acc[3][3] = fmaf(a3,b3,acc[3][3]);
    }
  }
  #pragma unroll
  for (int i = 0; i < 4; i++)
    #pragma unroll
    for (int j = 0; j < 4; j++)
      hn0[(size_t)(m0 + ty*4 + i) * 64 + tx*4 + j] = fmaxf(acc[i][j], 0.f);
}

// ---------------------- per-node combos (block per node) --------------------
template<int K>
__global__ __launch_bounds__(256) void an_node_k(const float* __restrict__ in, const float* __restrict__ wc,
                                                 float* __restrict__ an){
  __shared__ float row[K];
  const int n = blockIdx.x;
  const int t = threadIdx.x;
  for (int c = t; c < K; c += 256) row[c] = in[(size_t)n * K + c];
  __syncthreads();
  const int o = t >> 4, sub = t & 15;
  constexpr int CH = K / 16;
  float acc = 0.f;
  for (int c = 0; c < CH; c++)
    acc = fmaf(row[sub + 16*c], wc[o*K + sub + 16*c], acc);
  acc += __shfl_xor(acc, 1); acc += __shfl_xor(acc, 2);
  acc += __shfl_xor(acc, 4); acc += __shfl_xor(acc, 8);
  if (sub == 0) an[n * 16 + o] = acc;
}

// ------------------------------ small kernels -------------------------------
// Ub[e,d] = bf16(ebd[e,d] + hn0[src[e],d]) — 4 elems/thread
__global__ __launch_bounds__(256) void u_k(const void* __restrict__ ebd, const float* __restrict__ hn0,
                                           const int* __restrict__ src, u16* __restrict__ Ub,
                                           const int* __restrict__ flagp){
  const int fl = *flagp;
  const int id = blockIdx.x * 256 + threadIdx.x;    // < NEd*16
  const int e = id >> 4, d0 = (id & 15) * 4;
  const int sn = src[e];
  ushort4 o;
  o.x = f2bf(ldin(ebd, (size_t)e * 64 + d0 + 0, fl) + hn0[(size_t)sn * 64 + d0 + 0]);
  o.y = f2bf(ldin(ebd, (size_t)e * 64 + d0 + 1, fl) + hn0[(size_t)sn * 64 + d0 + 1]);
  o.z = f2bf(ldin(ebd, (size_t)e * 64 + d0 + 2, fl) + hn0[(size_t)sn * 64 + d0 + 2]);
  o.w = f2bf(ldin(ebd, (size_t)e * 64 + d0 + 3, fl) + hn0[(size_t)sn * 64 + d0 + 3]);
  *(ushort4*)(Ub + (size_t)e * 64 + d0) = o;
}

__global__ __launch_bounds__(256) void s1_k(const void* __restrict__ ebd, const float* __restrict__ cb,
                                            const int* __restrict__ src, const int* __restrict__ dst,
                                            const float* __restrict__ an, float* __restrict__ S,
                                            const int* __restrict__ flagp){
  const int fl = *flagp;
  const int id = blockIdx.x * 256 + threadIdx.x;
  const int e = id >> 3, h = id & 7;
  float a3 = 0.f;
  const float* w = cb + CB_WE1 + h * 64;
  for (int d = 0; d < 64; d++) a3 = fmaf(ldin(ebd, (size_t)e * 64 + d, fl), w[d], a3);
  const float a = an[src[e] * 16 + h] + a3 + an[dst[e] * 16 + 8 + h];
  S[id] = leaky(a);
}

// layer-1 segment softmax -> alpha (edge-id indexed)
__global__ __launch_bounds__(256) void segalpha_k(const float* __restrict__ S, const int* __restrict__ rp,
                                                  const int* __restrict__ cidx, float* __restrict__ AL){
  const int w = blockIdx.x * 4 + (threadIdx.x >> 6);
  const int lane = threadIdx.x & 63;
  const int n = w >> 3, h = w & 7;
  const int beg = rp[n], end = rp[n + 1];
  float m = -1e30f, z = 0.f;
  for (int base = beg; base < end; base += 64){
    const int idx = base + lane;
    float v = -1e30f, cc = 0.f;
    if (idx < end){ v = S[(size_t)cidx[idx] * 8 + h]; cc = 1.f; }
    lse_merge(m, z, v, cc);
  }
  #pragma unroll
  for (int off = 32; off; off >>= 1){
    float om = __shfl_xor(m, off), oz = __shfl_xor(z, off);
    lse_merge(m, z, om, oz);
  }
  const float rz = 1.f / fmaxf(z, 1e-9f);
  for (int base = beg; base < end; base += 64){
    const int idx = base + lane;
    if (idx < end){
      const int e = cidx[idx];
      AL[(size_t)e * 8 + h] = __expf(S[(size_t)e * 8 + h] - m) * rz;
    }
  }
}

// g1[n,h,d] — block per node (U is bf16 now)
__global__ __launch_bounds__(256) void g1b_k(const float* __restrict__ AL, const u16* __restrict__ Ub,
                                             const int* __restrict__ rp, const int* __restrict__ cidx,
                                             float* __restrict__ G1){
  const int n = blockIdx.x;
  const int t = threadIdx.x;
  const int d = t & 63, hh = t >> 6;
  const int beg = rp[n], end = rp[n + 1];
  float a0 = 0.f, a1 = 0.f;
  for (int idx = beg; idx < end; idx++){
    const int e = cidx[idx];
    const float uv = bf2f(Ub[(size_t)e * 64 + d]);
    a0 = fmaf(AL[(size_t)e * 8 + hh],     uv, a0);
    a1 = fmaf(AL[(size_t)e * 8 + hh + 4], uv, a1);
  }
  G1[(size_t)(n * 8 + hh)     * 64 + d] = a0;
  G1[(size_t)(n * 8 + hh + 4) * 64 + d] = a1;
}

// nft1 tiled GEMM: HNA[n, h*64+c] = elu( sum_k G1[n,h,k] * W1[k, h*64+c] )
__global__ __launch_bounds__(256) void nft1_tile_k(const float* __restrict__ G1, const float* __restrict__ wf,
                                                   float* __restrict__ HNA){
  __shared__ float At[64][65], Bt[64][65];
  const int t = threadIdx.x, tx = t & 15, ty = t >> 4;
  const int h = blockIdx.y;
  const int n0 = blockIdx.x * 64;
  {
    const int i = t >> 2, c0 = (t & 3) * 16;
    const float* gp = G1 + ((size_t)(n0 + i) * 8 + h) * 64 + c0;
    for (int c = 0; c < 16; c++) At[i][c0 + c] = gp[c];
    const int kk = t >> 2;
    const float* wp = wf + WO_W1 + (size_t)kk * 512 + h * 64 + c0;
    for (int c = 0; c < 16; c++) Bt[kk][c0 + c] = wp[c];
  }
  __syncthreads();
  float acc[4][4] = {{0.f}};
  #pragma unroll
  for (int k = 0; k < 64; k++){
    float a0 = At[ty*4+0][k], a1 = At[ty*4+1][k], a2 = At[ty*4+2][k], a3 = At[ty*4+3][k];
    float b0 = Bt[k][tx*4+0], b1 = Bt[k][tx*4+1], b2 = Bt[k][tx*4+2], b3 = Bt[k][tx*4+3];
    acc[0][0] = fmaf(a0,b0,acc[0][0]); acc[0][1] = fmaf(a0,b1,acc[0][1]); acc[0][2] = fmaf(a0,b2,acc[0][2]); acc[0][3] = fmaf(a0,b3,acc[0][3]);
    acc[1][0] = fmaf(a1,b0,acc[1][0]); acc[1][1] = fmaf(a1,b1,acc[1][1]); acc[1][2] = fmaf(a1,b2,acc[1][2]); acc[1][3] = fmaf(a1,b3,acc[1][3]);
    acc[2][0] = fmaf(a2,b0,acc[2][0]); acc[2][1] = fmaf(a2,b1,acc[2][1]); acc[2][2] = fmaf(a2,b2,acc[2][2]); acc[2][3] = fmaf(a2,b3,acc[2][3]);
    acc[3][0] = fmaf(a3,b0,acc[3][0]); acc[3][1] = fmaf(a3,b1,acc[3][1]); acc[3][2] = fmaf(a3,b2,acc[3][2]); acc[3][3] = fmaf(a3,b3,acc[3][3]);
  }
  #pragma unroll
  for (int i = 0; i < 4; i++)
    #pragma unroll
    for (int j = 0; j < 4; j++)
      HNA[(size_t)(n0 + ty*4 + i) * 512 + h * 64 + tx*4 + j] = eluf(acc[i][j]);
}

// y2: MFMA U@W1 + epilogue (elu(alpha*.)+HNA gather, bf16 Y store) + fused
// layer-2 score dot (S2 by CSR pos). Block = 64 slice positions.
__global__ __launch_bounds__(256) void y2_k(const u16* __restrict__ Ub, const float* __restrict__ AL1,
                                            const float* __restrict__ HNA, const u16* __restrict__ W1b,
                                            const float* __restrict__ cb, const float* __restrict__ AN2,
                                            const int* __restrict__ src, const int* __restrict__ dst,
                                            const int* __restrict__ cidx, u16* __restrict__ Y,
                                            float* __restrict__ SA, const int s){
  __shared__ __align__(16) u16 Us[64][72];
  __shared__ __align__(16) u16 Wst[64][72];   // Wst[c][k] per h-block
  __shared__ float als[8][64];
  __shared__ float Wt[512][8];                // WE2 transposed [c][h2]
  __shared__ int Es[64], Ss[64], Ds[64];
  const int t = threadIdx.x;
  const int w = t >> 6, lane = t & 63;
  const int col = lane & 15, quad = lane >> 4;
  const int ep0 = s * 16384 + blockIdx.x * 64;
  if (t < 64){ const int e = cidx[ep0 + t]; Es[t] = e; Ss[t] = src[e]; Ds[t] = dst[e]; }
  for (int idx = t; idx < 4096; idx += 256){
    const int c = idx >> 3, h2 = idx & 7;
    Wt[c][h2] = cb[CB_WE2 + h2 * 512 + c];
  }
  __syncthreads();
  {
    const int r = t >> 2, c0 = (t & 3) * 16;
    const u16* up = Ub + (size_t)Es[r] * 64 + c0;
    #pragma unroll
    for (int cc = 0; cc < 16; cc += 4)
      *(ushort4*)&Us[r][c0 + cc] = *(const ushort4*)(up + cc);
  }
  for (int idx = t; idx < 512; idx += 256){
    const int h = idx >> 6, i = idx & 63;
    als[h][i] = AL1[(size_t)Es[i] * 8 + h];
  }
  float sacc[4][8] = {{0.f}};
  for (int h = 0; h < 8; h++){
    __syncthreads();
    {
      const int d = t >> 2, c0 = (t & 3) * 16;
      const u16* wp = W1b + d * 512 + h * 64 + c0;
      for (int cc = 0; cc < 16; cc++) Wst[c0 + cc][d] = wp[cc];
    }
    __syncthreads();
    f32x4 acc[4];
    #pragma unroll
    for (int nt = 0; nt < 4; nt++) acc[nt] = (f32x4){0.f, 0.f, 0.f, 0.f};
    #pragma unroll
    for (int ks = 0; ks < 2; ks++){
      bf16x8 a = *(const bf16x8*)&Us[w*16 + col][ks*32 + quad*8];
      #pragma unroll
      for (int nt = 0; nt < 4; nt++){
        bf16x8 b = *(const bf16x8*)&Wst[nt*16 + col][ks*32 + quad*8];
        acc[nt] = __builtin_amdgcn_mfma_f32_16x16x32_bf16(a, b, acc[nt], 0, 0, 0);
      }
    }
    #pragma unroll
    for (int i = 0; i < 4; i++){
      const int er = w*16 + quad*4 + i;
      const float al = als[h][er];
      const size_t hb = (size_t)Ss[er] * 512 + h * 64;
      #pragma unroll
      for (int nt = 0; nt < 4; nt++){
        const int cl = nt*16 + col;
        const float v = eluf(al * acc[nt][i]) + HNA[hb + cl];
        Y[(size_t)(blockIdx.x*64 + er) * 512 + h*64 + cl] = f2bf(v);
        const float* wp = Wt[h*64 + cl];
        #pragma unroll
        for (int h2 = 0; h2 < 8; h2++) sacc[i][h2] = fmaf(v, wp[h2], sacc[i][h2]);
      }
    }
  }
  #pragma unroll
  for (int i = 0; i < 4; i++)
    #pragma unroll
    for (int h2 = 0; h2 < 8; h2++){
      float v = sacc[i][h2];
      v += __shfl_xor(v, 1); v += __shfl_xor(v, 2);
      v += __shfl_xor(v, 4); v += __shfl_xor(v, 8);
      sacc[i][h2] = v;
    }
  if (col == 0){
    #pragma unroll
    for (int i = 0; i < 4; i++){
      const int er = w*16 + quad*4 + i;
      const int se = Ss[er], de = Ds[er];
      const size_t pos = ep0 + er;
      #pragma unroll
      for (int h2 = 0; h2 < 8; h2++)
        SA[pos * 8 + h2] = leaky(AN2[se*16 + h2] + sacc[i][h2] + AN2[de*16 + 8 + h2]);
    }
  }
}

// layer-2 segment softmax, position-indexed, in-place S -> alpha
__global__ __launch_bounds__(256) void segalpha2_k(float* __restrict__ SA, const int* __restrict__ rp,
                                                   const int s){
  const int w = blockIdx.x * 4 + (threadIdx.x >> 6);
  const int lane = threadIdx.x & 63;
  const int n = s * 2048 + (w >> 3), h = w & 7;
  const int beg = rp[n], end = rp[n + 1];
  float m = -1e30f, z = 0.f;
  for (int base = beg; base < end; base += 64){
    const int idx = base + lane;
    float v = -1e30f, cc = 0.f;
    if (idx < end){ v = SA[(size_t)idx * 8 + h]; cc = 1.f; }
    lse_merge(m, z, v, cc);
  }
  #pragma unroll
  for (int off = 32; off; off >>= 1){
    float om = __shfl_xor(m, off), oz = __shfl_xor(z, off);
    lse_merge(m, z, om, oz);
  }
  const float rz = 1.f / fmaxf(z, 1e-9f);
  for (int base = beg; base < end; base += 64){
    const int idx = base + lane;
    if (idx < end)
      SA[(size_t)idx * 8 + h] = __expf(SA[(size_t)idx * 8 + h] - m) * rz;
  }
}

// slice g2 (bf16): g2[nl,h,c] = sum_pos alpha2[pos,h]*y[epl,c]
__global__ __launch_bounds__(256) void g2_k(const float* __restrict__ SA, const u16* __restrict__ Y,
                                            const int* __restrict__ rp, u16* __restrict__ G2, const int s){
  const int t = threadIdx.x;
  const int nl = blockIdx.x;
  const int n = s * 2048 + nl;
  const int d4 = (t & 127) * 4;
  const int hh = (t >> 7) * 4;
  const int beg = rp[n], end = rp[n + 1];
  const int base = s * 16384;
  float acc[4][4] = {{0.f}};
  for (int pos = beg; pos < end; pos++){
    const int epl = pos - base;
    const float4 a4 = *(const float4*)(SA + (size_t)pos * 8 + hh);
    const ushort4 yv = *(const ushort4*)(Y + (size_t)epl * 512 + d4);
    const float y0 = bf2f(yv.x), y1 = bf2f(yv.y), y2 = bf2f(yv.z), y3 = bf2f(yv.w);
    acc[0][0] = fmaf(a4.x, y0, acc[0][0]); acc[0][1] = fmaf(a4.x, y1, acc[0][1]); acc[0][2] = fmaf(a4.x, y2, acc[0][2]); acc[0][3] = fmaf(a4.x, y3, acc[0][3]);
    acc[1][0] = fmaf(a4.y, y0, acc[1][0]); acc[1][1] = fmaf(a4.y, y1, acc[1][1]); acc[1][2] = fmaf(a4.y, y2, acc[1][2]); acc[1][3] = fmaf(a4.y, y3, acc[1][3]);
    acc[2][0] = fmaf(a4.z, y0, acc[2][0]); acc[2][1] = fmaf(a4.z, y1, acc[2][1]); acc[2][2] = fmaf(a4.z, y2, acc[2][2]); acc[2][3] = fmaf(a4.z, y3, acc[2][3]);
    acc[3][0] = fmaf(a4.w, y0, acc[3][0]); acc[3][1] = fmaf(a4.w, y1, acc[3][1]); acc[3][2] = fmaf(a4.w, y2, acc[3][2]); acc[3][3] = fmaf(a4.w, y3, acc[3][3]);
  }
  #pragma unroll
  for (int hi = 0; hi < 4; hi++)
    #pragma unroll
    for (int di = 0; di < 4; di++)
      G2[((size_t)nl * 8 + hh + hi) * 512 + d4 + di] = f2bf(acc[hi][di]);
}

// slice nft2: hnB16[n, h*64+c] = elu( sum_k g2[nl,h,k] * W2[k, h*64+c] )
__global__ __launch_bounds__(256) void nft2_k(const u16* __restrict__ G2, const float* __restrict__ wf,
                                              u16* __restrict__ HNB, const int s){
  __shared__ float At[64][65], Bt[64][65];
  const int t = threadIdx.x, tx = t & 15, ty = t >> 4;
  const int h = blockIdx.y;
  const int nl0 = blockIdx.x * 64;
  float acc[4][4] = {{0.f}};
  for (int kt = 0; kt < 512; kt += 64){
    __syncthreads();
    {
      const int i = t >> 2, c0 = (t & 3) * 16;
      const u16* gp = G2 + ((size_t)(nl0 + i) * 8 + h) * 512 + kt + c0;
      for (int c = 0; c < 16; c++) At[i][c0 + c] = bf2f(gp[c]);
      const int kk = t >> 2;
      const float* wp = wf + WO_W2 + (size_t)(kt + kk) * 512 + h * 64 + c0;
      for (int c = 0; c < 16; c++) Bt[kk][c0 + c] = wp[c];
    }
    __syncthreads();
    #pragma unroll
    for (int k = 0; k < 64; k++){
      float a0 = At[ty*4+0][k], a1 = At[ty*4+1][k], a2 = At[ty*4+2][k], a3 = At[ty*4+3][k];
      float b0 = Bt[k][tx*4+0], b1 = Bt[k][tx*4+1], b2 = Bt[k][tx*4+2], b3 = Bt[k][tx*4+3];
      acc[0][0] = fmaf(a0,b0,acc[0][0]); acc[0][1] = fmaf(a0,b1,acc[0][1]); acc[0][2] = fmaf(a0,b2,acc[0][2]); acc[0][3] = fmaf(a0,b3,acc[0][3]);
      acc[1][0] = fmaf(a1,b0,acc[1][0]); acc[1][1] = fmaf(a1,b1,acc[1][1]); acc[1][2] = fmaf(a1,b2,acc[1][2]); acc[1][3] = fmaf(a1,b3,acc[1][3]);
      acc[2][0] = fmaf(a2,b0,acc[2][0]); acc[2][1] = fmaf(a2,b1,acc[2][1]); acc[2][2] = fmaf(a2,b2,acc[2][2]); acc[2][3] = fmaf(a2,b3,acc[2][3]);
      acc[3][0] = fmaf(a3,b0,acc[3][0]); acc[3][1] = fmaf(a3,b1,acc[3][1]); acc[3][2] = fmaf(a3,b2,acc[3][2]); acc[3][3] = fmaf(a3,b3,acc[3][3]);
    }
  }
  #pragma unroll
  for (int i = 0; i < 4; i++)
    #pragma unroll
    for (int j = 0; j < 4; j++)
      HNB[(size_t)(s * 2048 + nl0 + ty*4 + i) * 512 + h * 64 + tx*4 + j] = f2bf(eluf(acc[i][j]));
}

// ---------------------------------- CSR -------------------------------------
__global__ __launch_bounds__(256) void hist_k(const int* __restrict__ dst, int* __restrict__ deg){
  const int e = blockIdx.x * 256 + threadIdx.x;
  if (e < NEd) atomicAdd(&deg[dst[e]], 1);
}
__global__ __launch_bounds__(256) void scan_k(const int* __restrict__ deg, int* __restrict__ rp,
                                              int* __restrict__ fill){
  __shared__ int ps[257];
  const int t = threadIdx.x;
  const int base = t * 64;
  int s = 0;
  for (int i = 0; i < 64; i++) s += deg[base + i];
  ps[t + 1] = s;
  if (t == 0) ps[0] = 0;
  __syncthreads();
  if (t == 0) for (int i = 1; i <= 256; i++) ps[i] += ps[i - 1];
  __syncthreads();
  int off = ps[t];
  for (int i = 0; i < 64; i++){ rp[base + i] = off; fill[base + i] = off; off += deg[base + i]; }
  if (t == 255) rp[NNd] = off;
}
__global__ __launch_bounds__(256) void scatter_k(const int* __restrict__ dst, int* __restrict__ fill,
                                                 int* __restrict__ cidx){
  const int e = blockIdx.x * 256 + threadIdx.x;
  if (e < NEd){ int pos = atomicAdd(&fill[dst[e]], 1); cidx[pos] = e; }
}

// ------------------------------- readout ------------------------------------
// block per subgraph; thread owns 2 columns; row-major coalesced sweep
__global__ __launch_bounds__(256) void mean_k(const u16* __restrict__ HNB, float* __restrict__ xcat){
  const int sg = blockIdx.x;   // 0..31
  const int t = threadIdx.x;
  const int g = (sg < 16) ? sg : sg - 16;
  const int half = (sg < 16) ? 0 : 1;
  const int c0 = t * 2;
  float s0 = 0.f, s1 = 0.f;
  const u16* base = HNB + (size_t)sg * 512 * 512;
  for (int n = 0; n < 512; n++){
    const u32 u = *(const u32*)(base + (size_t)n * 512 + c0);
    s0 += bf2f((u16)(u & 0xffffu));
    s1 += bf2f((u16)(u >> 16));
  }
  xcat[g * 1024 + half * 512 + c0]     = s0 * (1.f / 512.f);
  xcat[g * 1024 + half * 512 + c0 + 1] = s1 * (1.f / 512.f);
}

__global__ __launch_bounds__(1024) void head_k(float* __restrict__ xcat, const float* __restrict__ wf,
                                               void* __restrict__ outp, const int* __restrict__ flagp){
  __shared__ float y1[16][64];
  __shared__ float y2[16][64];
  __shared__ float mu2s[64], sc2s[64];
  const int t = threadIdx.x;
  {
    float mu = 0.f;
    #pragma unroll
    for (int g = 0; g < 16; g++) mu += xcat[g * 1024 + t];
    mu *= (1.f / 16.f);
    float var = 0.f;
    #pragma unroll
    for (int g = 0; g < 16; g++){ float d = xcat[g * 1024 + t] - mu; var += d * d; }
    var *= (1.f / 16.f);
    const float sc = rsqrtf(var + 1e-5f) * wf[WO_B1G + t];
    const float sh = wf[WO_B1B + t] - mu * sc;
    #pragma unroll
    for (int g = 0; g < 16; g++) xcat[g * 1024 + t] = xcat[g * 1024 + t] * sc + sh;
  }
  __syncthreads();
  {
    const int gg = t >> 6, c = t & 63;
    float acc = wf[WO_F1B + c];
    for (int k = 0; k < 1024; k++) acc = fmaf(xcat[gg * 1024 + k], wf[WO_F1W + k * 64 + c], acc);
    y1[gg][c] = fmaxf(acc, 0.f);
  }
  __syncthreads();
  if (t < 64){
    float mu = 0.f;
    #pragma unroll
    for (int g = 0; g < 16; g++) mu += y1[g][t];
    mu *= (1.f / 16.f);
    float var = 0.f;
    #pragma unroll
    for (int g = 0; g < 16; g++){ float d = y1[g][t] - mu; var += d * d; }
    var *= (1.f / 16.f);
    mu2s[t] = mu; sc2s[t] = rsqrtf(var + 1e-5f) * wf[WO_B2G + t];
  }
  __syncthreads();
  {
    const int gg = t >> 6, c = t & 63;
    y2[gg][c] = (y1[gg][c] - mu2s[c]) * sc2s[c] + wf[WO_B2B + c];
  }
  __syncthreads();
  if (t < 48){
    const int gg = t / 3, c = t % 3;
    float acc = wf[WO_F2B + c];
    #pragma unroll
    for (int k = 0; k < 64; k++) acc = fmaf(y2[gg][k], wf[WO_F2W + k * 3 + c], acc);
    if (*flagp) ((u16*)outp)[t] = f2bf(acc);
    else        ((float*)outp)[t] = acc;
  }
}

// --------------------------------- launch -----------------------------------
extern "C" void kernel_launch(void* const* d_in, const int* in_sizes, int n_in,
                              void* d_out, int out_size, void* d_ws, size_t ws_size,
                              hipStream_t stream) {
  (void)in_sizes; (void)n_in; (void)out_size;
  if (ws_size < WS_NEED) return;

  const int* src = (const int*)d_in[3];
  const int* dst = (const int*)d_in[4];
  char* w = (char*)d_ws;

  float* wf   = (float*)(w + OFF_WF);
  float* cb   = (float*)(w + OFF_CB);
  u16*   Ub   = (u16*)(w + OFF_U);
  u16*   W1b  = (u16*)(w + OFF_W1B);
  float* AL1  = (float*)(w + OFF_AL1);
  float* SA   = (float*)(w + OFF_SA);
  float* HNA  = (float*)(w + OFF_HNA);
  int*   deg  = (int*)(w + OFF_DEG);
  int*   rp   = (int*)(w + OFF_RP);
  int*   fill = (int*)(w + OFF_FILL);
  int*   cidx = (int*)(w + OFF_CIDX);
  float* rbig = (float*)(w + OFF_RBIG);
  float* xcat = (float*)(w + OFF_XCAT);
  int*   flag = (int*)(w + OFF_FLAG);

  float* x1a  = (float*)(w + OFF_T + T_X1A);
  float* x2a  = (float*)(w + OFF_T + T_X2A);
  float* hn0  = (float*)(w + OFF_T + T_HN0);
  float* AN1  = (float*)(w + OFF_T + T_AN1);
  float* S    = (float*)(w + OFF_T + T_S);
  u16*   Y    = (u16*)(w + OFF_T + T_Y);
  u16*   G2   = (u16*)(w + OFF_T + T_G2);

  float* pacc = rbig;
  float* pm   = (float*)(w + OFF_RBIG + R_PM);
  float* pz   = (float*)(w + OFF_RBIG + R_PZ);
  float* G1   = rbig;                              // layer-1 phase
  u16*   HNB  = (u16*)(w + OFF_RBIG);              // slice phase (bf16)
  float* AN2  = (float*)(w + OFF_RBIG + R_AN2);

  // 0. detect + weights + combos
  detect_k<<<1, 256, 0, stream>>>((const u16*)d_in[0], flag);
  P17 ps;
  for (int i = 0; i < 17; i++) ps.p[i] = d_in[6 + i];
  convw_k<<<(WO_END + 255) / 256, 256, 0, stream>>>(ps, wf, flag);
  convw1b_k<<<128, 256, 0, stream>>>(wf, W1b);
  combos_k<<<(CB_END + 255) / 256, 256, 0, stream>>>(wf, cb);

  // 1. CSR over dst
  hipMemsetAsync(deg, 0, NNd * sizeof(int), stream);
  hist_k<<<NEd / 256, 256, 0, stream>>>(dst, deg);
  scan_k<<<1, 256, 0, stream>>>(deg, rp, fill);
  scatter_k<<<NEd / 256, 256, 0, stream>>>(dst, fill, cidx);

  // 2. alignment (MFMA flash)
  flash_mfma_k<<<dim3(128, 4), 256, 0, stream>>>(d_in[0], d_in[1], flag, pacc, pm, pz);
  flash_merge_k<<<NSd / 4, 256, 0, stream>>>(pacc, pm, pz, x1a);
  flash_mfma_k<<<dim3(128, 4), 256, 0, stream>>>(d_in[1], d_in[0], flag, pacc, pm, pz);
  flash_merge_k<<<NSd / 4, 256, 0, stream>>>(pacc, pm, pz, x2a);

  // 3. projection
  proj_k<<<NNd / 64, 256, 0, stream>>>(d_in[0], d_in[1], x1a, x2a, wf, hn0, flag);

  // 4. GAT layer 1
  an_node_k<64><<<NNd, 256, 0, stream>>>(hn0, cb + CB_WC1, AN1);
  u_k<<<NEd * 16 / 256, 256, 0, stream>>>(d_in[2], hn0, src, Ub, flag);
  s1_k<<<NEd * 8 / 256, 256, 0, stream>>>(d_in[2], cb, src, dst, AN1, S, flag);
  segalpha_k<<<NNd * 8 / 4, 256, 0, stream>>>(S, rp, cidx, AL1);
  g1b_k<<<NNd, 256, 0, stream>>>(AL1, Ub, rp, cidx, G1);
  nft1_tile_k<<<dim3(NNd / 64, 8), 256, 0, stream>>>(G1, wf, HNA);

  // 5. layer-2 per-node combos
  an_node_k<512><<<NNd, 256, 0, stream>>>(HNA, cb + CB_WC2, AN2);

  // 6. layer-2: 8 slices (y2 fuses Y build + score dot)
  for (int s = 0; s < 8; s++){
    y2_k<<<256, 256, 0, stream>>>(Ub, AL1, HNA, W1b, cb, AN2, src, dst, cidx, Y, SA, s);
    segalpha2_k<<<4096, 256, 0, stream>>>(SA, rp, s);
    g2_k<<<2048, 256, 0, stream>>>(SA, Y, rp, G2, s);
    nft2_k<<<dim3(32, 8), 256, 0, stream>>>(G2, wf, HNB, s);
  }

  // 7. readout
  mean_k<<<32, 256, 0, stream>>>(HNB, xcat);
  head_k<<<1, 1024, 0, stream>>>(xcat, wf, d_out, flag);
}